// Round 10
// baseline (831.846 us; speedup 1.0000x reference)
//
#include <hip/hip_runtime.h>
#include <math.h>

#define NNODES 20000
#define NPAD   20096   // 157 * 128
#define NEDGES 160000
#define HIDDIM 128
#define NHEADS 8
#define NGRAPH 64
#define KC 384   // concatenated K (hi | lo | hi)
#define GXTILES 157

typedef short short8 __attribute__((ext_vector_type(8)));
typedef float floatx4 __attribute__((ext_vector_type(4)));
typedef unsigned short ushort4v __attribute__((ext_vector_type(4)));

__device__ inline unsigned short f2bf(float x) {
    unsigned u = __float_as_uint(x);
    u += 0x7fff + ((u >> 16) & 1);
    return (unsigned short)(u >> 16);
}
__device__ inline float bf2f(unsigned short h) {
    return __uint_as_float(((unsigned)h) << 16);
}

// ---------------- utility ----------------
__global__ __launch_bounds__(256) void zero_kernel(float* __restrict__ p, int n) {
    int i = blockIdx.x * blockDim.x + threadIdx.x;
    if (i < n) p[i] = 0.f;
}

// ---------------- CSR build ----------------
__global__ __launch_bounds__(256) void count_deg_kernel(const int* __restrict__ dst,
                                                        int* __restrict__ deg, int e) {
    int i = blockIdx.x * blockDim.x + threadIdx.x;
    if (i < e) atomicAdd(&deg[dst[i]], 1);
}

__global__ __launch_bounds__(256) void scan1_kernel(const int* __restrict__ deg,
                                                    int* __restrict__ chunk,
                                                    int* __restrict__ bsum, int n) {
    __shared__ int buf[256];
    int t = threadIdx.x;
    int i = blockIdx.x * 256 + t;
    int v = (i < n) ? deg[i] : 0;
    buf[t] = v;
    __syncthreads();
    for (int off = 1; off < 256; off <<= 1) {
        int tmp = (t >= off) ? buf[t - off] : 0;
        __syncthreads();
        buf[t] += tmp;
        __syncthreads();
    }
    if (i < n) chunk[i] = buf[t];
    if (t == 255) bsum[blockIdx.x] = buf[255];
}

__global__ __launch_bounds__(128) void scan2_kernel(int* __restrict__ bsum, int nb) {
    __shared__ int buf[128];
    int t = threadIdx.x;
    int v = (t < nb) ? bsum[t] : 0;
    buf[t] = v;
    __syncthreads();
    for (int off = 1; off < 128; off <<= 1) {
        int tmp = (t >= off) ? buf[t - off] : 0;
        __syncthreads();
        buf[t] += tmp;
        __syncthreads();
    }
    if (t < nb) bsum[t] = buf[t] - v;
}

__global__ __launch_bounds__(256) void scan3_kernel(const int* __restrict__ chunk,
                                                    const int* __restrict__ bsum,
                                                    int* __restrict__ offs, int n) {
    int i = blockIdx.x * 256 + threadIdx.x;
    if (i < n) offs[i + 1] = chunk[i] + bsum[i >> 8];
    if (i == 0) offs[0] = 0;
}

__global__ __launch_bounds__(256) void scatter_kernel(const int* __restrict__ src,
                                                      const int* __restrict__ dst,
                                                      const int* __restrict__ offs,
                                                      int* __restrict__ cursor,
                                                      int* __restrict__ csr_src, int e) {
    int i = blockIdx.x * blockDim.x + threadIdx.x;
    if (i < e) {
        int d = dst[i];
        int pos = offs[d] + atomicAdd(&cursor[d], 1);
        csr_src[pos] = src[i];
    }
}

// ---------------- weight prep ----------------
__global__ __launch_bounds__(128) void prep_w_kernel(
    const float* __restrict__ Wq, const float* __restrict__ Wk,
    const float* __restrict__ Wv, const float* __restrict__ Ws,
    const float* __restrict__ Wp, const float* __restrict__ Ws3,
    const float* __restrict__ Wq3, const float* __restrict__ Wk3,
    const float* __restrict__ Wv3, unsigned short* __restrict__ WtAll) {
    int id = blockIdx.x;
    int k = threadIdx.x;
    float w;
    if (id < 1536) {
        int li = id / 512, n = id % 512, sel = n >> 7, np = n & 127;
        const float* W = (sel == 0) ? Wq : (sel == 1) ? Ws : (sel == 2) ? Wk : Wv;
        w = W[li * 16384 + k * 128 + np];
    } else if (id < 1664) {
        w = Wp[k * 128 + (id - 1536)];
    } else if (id < 1792) {
        w = Ws3[k * 128 + (id - 1664)];
    } else if (id < 2816) {
        int r = id - 1792, h = r >> 7, j = r & 127;
        w = Wq3[k * 1024 + h * 128 + j];
    } else {
        int r = id - 2816, h = r >> 8, jj = r & 255;
        const float* W = (jj < 128) ? Wk3 : Wv3;
        w = W[k * 1024 + h * 128 + (jj & 127)];
    }
    unsigned short hi = f2bf(w);
    unsigned short lo = f2bf(w - bf2f(hi));
    unsigned short* dst = WtAll + (size_t)id * KC;
    dst[k] = hi;
    dst[128 + k] = hi;
    dst[256 + k] = lo;
}

__global__ __launch_bounds__(256) void prep_bias_kernel(
    const float* __restrict__ bq, const float* __restrict__ bk,
    const float* __restrict__ bv, const float* __restrict__ bs,
    const float* __restrict__ bq3, const float* __restrict__ bk3,
    const float* __restrict__ bv3, float* __restrict__ bcat) {
    int id = blockIdx.x * 256 + threadIdx.x;
    if (id >= 4608) return;
    float v;
    if (id < 1536) {
        int li = id / 512, n = id % 512, sel = n >> 7, np = n & 127;
        const float* b = (sel == 0) ? bq : (sel == 1) ? bs : (sel == 2) ? bk : bv;
        v = b[li * 128 + np];
    } else if (id < 2560) {
        v = bq3[id - 1536];
    } else {
        int r = id - 2560, h = r >> 8, jj = r & 255;
        const float* b = (jj < 128) ? bk3 : bv3;
        v = b[h * 128 + (jj & 127)];
    }
    bcat[id] = v;
}

// ---------------- activation -> split-bf16 A_cat ----------------
__global__ __launch_bounds__(256) void cat_from_kernel(const float* __restrict__ h,
                                                       unsigned short* __restrict__ Acat) {
    int idx = blockIdx.x * 256 + threadIdx.x;
    if (idx >= NPAD * HIDDIM) return;
    int r = idx >> 7, k = idx & 127;
    float x = (r < NNODES) ? h[idx] : 0.f;
    unsigned short hi = f2bf(x);
    unsigned short lo = f2bf(x - bf2f(hi));
    unsigned short* row = Acat + (size_t)r * KC;
    row[k] = hi;
    row[128 + k] = lo;
    row[256 + k] = hi;
}

// ---------------- MFMA GEMM (XCD swizzle + LDS-transposed coalesced epilogue) ----------------
// 1-D grid of 160*BY blocks; xcd = id&7, bx = (idx/BY)*8+xcd, by = idx%BY: all
// column passes of an A stripe stay on one XCD (A L2-resident -> FETCH ~logical).
// Epilogue: acc quads -> LDS (padded stride), then contiguous per-node-row
// copies to global (full-line writes; kills the 8B-per-line scatter).
template <typename OutT, int KG, int BY>
__global__ __launch_bounds__(256) void gemm_mfma_kernel(
    const unsigned short* __restrict__ Acat, const unsigned short* __restrict__ Wt,
    const float* __restrict__ bias, OutT* __restrict__ C, int M, int nrows) {
    constexpr int ROWW = (sizeof(OutT) == 2) ? 68 : 132;  // LDS row stride (words), padded
    __shared__ unsigned int Cs[64 * ROWW];
    int id = blockIdx.x;
    int xcd = id & 7;
    int idx = id >> 3;
    int bx = (idx / BY) * 8 + xcd;
    int by = idx % BY;
    if (bx >= GXTILES) return;
    int tt = threadIdx.x;
    int lane = tt & 63;
    int wave = tt >> 6;
    int nodeBase = bx * 128 + (wave & 1) * 64;
    int featLoc = (wave >> 1) * 64;       // feature offset within the 128-wide tile
    int featBase = by * 128 + featLoc;
    int m = lane & 15;
    int q = lane >> 4;
    int ko = q * 8;
    const unsigned short* wptr = Wt + (size_t)(featBase + m) * KC + ko;    // A operand
    const unsigned short* aptr = Acat + (size_t)(nodeBase + m) * KC + ko;  // B operand
    floatx4 acc[4][4];  // [feat tile r][node tile c]
#pragma unroll
    for (int r = 0; r < 4; ++r)
#pragma unroll
        for (int c = 0; c < 4; ++c) acc[r][c] = (floatx4){0.f, 0.f, 0.f, 0.f};
#pragma unroll
    for (int kg = 0; kg < KG; ++kg) {
        short8 a[4], b[4];
#pragma unroll
        for (int r = 0; r < 4; ++r) a[r] = *(const short8*)(wptr + (size_t)r * 16 * KC + kg * 32);
#pragma unroll
        for (int c = 0; c < 4; ++c) b[c] = *(const short8*)(aptr + (size_t)c * 16 * KC + kg * 32);
#pragma unroll
        for (int r = 0; r < 4; ++r)
#pragma unroll
            for (int c = 0; c < 4; ++c)
                acc[r][c] = __builtin_amdgcn_mfma_f32_16x16x32_bf16(a[r], b[c], acc[r][c], 0, 0, 0);
    }
    // ---- epilogue: two node-half phases through LDS ----
#pragma unroll
    for (int ph = 0; ph < 2; ++ph) {
        if ((wave & 1) == ph) {
#pragma unroll
            for (int r = 0; r < 4; ++r) {
                int fl = featLoc + r * 16 + q * 4;
                float4 bv = *(const float4*)(bias + by * 128 + fl);
#pragma unroll
                for (int c = 0; c < 4; ++c) {
                    int row = c * 16 + m;  // local node 0..63
                    float v0 = acc[r][c][0] + bv.x;
                    float v1 = acc[r][c][1] + bv.y;
                    float v2 = acc[r][c][2] + bv.z;
                    float v3 = acc[r][c][3] + bv.w;
                    if (sizeof(OutT) == 2) {
                        ushort4v o = {f2bf(v0), f2bf(v1), f2bf(v2), f2bf(v3)};
                        *(ushort4v*)((unsigned short*)Cs + (size_t)row * (ROWW * 2) + fl) = o;
                    } else {
                        float4 o = {v0, v1, v2, v3};
                        *(float4*)((float*)Cs + (size_t)row * ROWW + fl) = o;
                    }
                }
            }
        }
        __syncthreads();
        int node = tt & 63;
        int qtr = tt >> 6;
        int nodeG = bx * 128 + ph * 64 + node;
        if (nodeG < nrows) {
            const uint4* src = (const uint4*)((const char*)Cs + (size_t)node * ROWW * 4 +
                                              qtr * 32 * sizeof(OutT));
            uint4* dst = (uint4*)((char*)C + ((size_t)nodeG * M + by * 128 + qtr * 32) * sizeof(OutT));
            constexpr int NIT = (32 * sizeof(OutT)) / 16;
#pragma unroll
            for (int i = 0; i < NIT; ++i) dst[i] = src[i];
        }
        __syncthreads();
    }
}

// ---------------- attention layers 0-2: 2 edge slots x (8 heads x 4 lanes) ----------------
__global__ __launch_bounds__(64) void attn_small_kernel(
    const float* __restrict__ qs, const unsigned short* __restrict__ kv,
    const float* __restrict__ Wb,
    const int* __restrict__ offs, const int* __restrict__ csr_src,
    float* __restrict__ out) {
    int i = blockIdx.x;
    int l = threadIdx.x;
    int g = l >> 5;
    int d0 = (l & 31) * 4;
    float4 qv = *(const float4*)(qs + (size_t)i * 256 + d0);
    int e0 = offs[i], e1 = offs[i + 1];
    float mm = -1e30f, lac = 0.f;
    float a0 = 0.f, a1 = 0.f, a2 = 0.f, a3 = 0.f;
    for (int e = e0 + g; e < e1; e += 2) {
        int sn = csr_src[e];
        const unsigned short* row = kv + (size_t)sn * 256;
        uint2 kk = *(const uint2*)(row + d0);
        uint2 vv = *(const uint2*)(row + 128 + d0);
        float k0 = bf2f((unsigned short)(kk.x & 0xffff)), k1 = bf2f((unsigned short)(kk.x >> 16));
        float k2 = bf2f((unsigned short)(kk.y & 0xffff)), k3 = bf2f((unsigned short)(kk.y >> 16));
        float p = qv.x * k0 + qv.y * k1 + qv.z * k2 + qv.w * k3;
        p += __shfl_xor(p, 1);
        p += __shfl_xor(p, 2);
        float logit = p * 0.25f;
        float mnew = fmaxf(mm, logit);
        float sc = __expf(mm - mnew);
        float w = __expf(logit - mnew);
        float v0 = bf2f((unsigned short)(vv.x & 0xffff)), v1 = bf2f((unsigned short)(vv.x >> 16));
        float v2 = bf2f((unsigned short)(vv.y & 0xffff)), v3 = bf2f((unsigned short)(vv.y >> 16));
        a0 = a0 * sc + w * v0;
        a1 = a1 * sc + w * v1;
        a2 = a2 * sc + w * v2;
        a3 = a3 * sc + w * v3;
        lac = lac * sc + w;
        mm = mnew;
    }
    float mo = __shfl_xor(mm, 32), lo = __shfl_xor(lac, 32);
    float b0 = __shfl_xor(a0, 32), b1 = __shfl_xor(a1, 32);
    float b2 = __shfl_xor(a2, 32), b3 = __shfl_xor(a3, 32);
    float ms = fmaxf(mm, mo);
    float s0 = __expf(mm - ms), s1 = __expf(mo - ms);
    a0 = a0 * s0 + b0 * s1;
    a1 = a1 * s0 + b1 * s1;
    a2 = a2 * s0 + b2 * s1;
    a3 = a3 * s0 + b3 * s1;
    lac = lac * s0 + lo * s1;
    float inv = 1.f / (lac + 1e-16f);
    float o0 = a0 * inv, o1 = a1 * inv, o2 = a2 * inv, o3 = a3 * inv;
    float4 rv = *(const float4*)(qs + (size_t)i * 256 + 128 + d0);
    float part = o0 * Wb[d0] + o1 * Wb[d0 + 1] + o2 * Wb[d0 + 2] + o3 * Wb[d0 + 3]
               + rv.x * Wb[128 + d0] + rv.y * Wb[128 + d0 + 1]
               + rv.z * Wb[128 + d0 + 2] + rv.w * Wb[128 + d0 + 3]
               + (o0 - rv.x) * Wb[256 + d0] + (o1 - rv.y) * Wb[256 + d0 + 1]
               + (o2 - rv.z) * Wb[256 + d0 + 2] + (o3 - rv.w) * Wb[256 + d0 + 3];
    if (g) part = 0.f;
#pragma unroll
    for (int msk = 1; msk <= 32; msk <<= 1) part += __shfl_xor(part, msk);
    float gg = 1.f / (1.f + __expf(-part));
    if (g == 0) {
        float4 o4 = {gg * rv.x + (1.f - gg) * o0, gg * rv.y + (1.f - gg) * o1,
                     gg * rv.z + (1.f - gg) * o2, gg * rv.w + (1.f - gg) * o3};
        *(float4*)(out + (size_t)i * HIDDIM + d0) = o4;
    }
}

// ---------------- attention layer 3: 4 edge slots x 16 lanes x 8 dims ----------------
__global__ __launch_bounds__(64) void attn_big_kernel(
    const unsigned short* __restrict__ q3, const unsigned short* __restrict__ kv3,
    const int* __restrict__ offs, const int* __restrict__ csr_src,
    float* __restrict__ oslice) {
    int i = blockIdx.x;
    int y = blockIdx.y;
    int l = threadIdx.x;
    int g = l >> 4;
    int s = l & 15;
    uint4 qq = *(const uint4*)(q3 + (size_t)i * 512 + y * 128 + 8 * s);
    float q0 = bf2f((unsigned short)(qq.x & 0xffff)), q1 = bf2f((unsigned short)(qq.x >> 16));
    float q2 = bf2f((unsigned short)(qq.y & 0xffff)), q3f = bf2f((unsigned short)(qq.y >> 16));
    float q4 = bf2f((unsigned short)(qq.z & 0xffff)), q5 = bf2f((unsigned short)(qq.z >> 16));
    float q6 = bf2f((unsigned short)(qq.w & 0xffff)), q7 = bf2f((unsigned short)(qq.w >> 16));
    int e0 = offs[i], e1 = offs[i + 1];
    float mm = -1e30f, lac = 0.f;
    float ac[8];
#pragma unroll
    for (int j = 0; j < 8; ++j) ac[j] = 0.f;
    for (int e = e0 + g; e < e1; e += 4) {
        int sn = csr_src[e];
        const unsigned short* row = kv3 + (size_t)sn * 1024 + y * 256 + 8 * s;
        uint4 kk = *(const uint4*)row;
        uint4 vv = *(const uint4*)(row + 128);
        float k0 = bf2f((unsigned short)(kk.x & 0xffff)), k1 = bf2f((unsigned short)(kk.x >> 16));
        float k2 = bf2f((unsigned short)(kk.y & 0xffff)), k3 = bf2f((unsigned short)(kk.y >> 16));
        float k4 = bf2f((unsigned short)(kk.z & 0xffff)), k5 = bf2f((unsigned short)(kk.z >> 16));
        float k6 = bf2f((unsigned short)(kk.w & 0xffff)), k7 = bf2f((unsigned short)(kk.w >> 16));
        float p = q0 * k0 + q1 * k1 + q2 * k2 + q3f * k3
                + q4 * k4 + q5 * k5 + q6 * k6 + q7 * k7;
        p += __shfl_xor(p, 1);
        p += __shfl_xor(p, 2);
        p += __shfl_xor(p, 4);
        p += __shfl_xor(p, 8);
        float logit = p * 0.08838834764831845f;
        float mnew = fmaxf(mm, logit);
        float sc = __expf(mm - mnew);
        float w = __expf(logit - mnew);
        float v0 = bf2f((unsigned short)(vv.x & 0xffff)), v1 = bf2f((unsigned short)(vv.x >> 16));
        float v2 = bf2f((unsigned short)(vv.y & 0xffff)), v3 = bf2f((unsigned short)(vv.y >> 16));
        float v4 = bf2f((unsigned short)(vv.z & 0xffff)), v5 = bf2f((unsigned short)(vv.z >> 16));
        float v6 = bf2f((unsigned short)(vv.w & 0xffff)), v7 = bf2f((unsigned short)(vv.w >> 16));
        ac[0] = ac[0] * sc + w * v0; ac[1] = ac[1] * sc + w * v1;
        ac[2] = ac[2] * sc + w * v2; ac[3] = ac[3] * sc + w * v3;
        ac[4] = ac[4] * sc + w * v4; ac[5] = ac[5] * sc + w * v5;
        ac[6] = ac[6] * sc + w * v6; ac[7] = ac[7] * sc + w * v7;
        lac = lac * sc + w;
        mm = mnew;
    }
#pragma unroll
    for (int msk = 16; msk <= 32; msk <<= 1) {
        float mo = __shfl_xor(mm, msk), lo = __shfl_xor(lac, msk);
        float bo[8];
#pragma unroll
        for (int j = 0; j < 8; ++j) bo[j] = __shfl_xor(ac[j], msk);
        float ms = fmaxf(mm, mo);
        float s0 = __expf(mm - ms), s1 = __expf(mo - ms);
#pragma unroll
        for (int j = 0; j < 8; ++j) ac[j] = ac[j] * s0 + bo[j] * s1;
        lac = lac * s0 + lo * s1;
        mm = ms;
    }
    if (g == 0) {
        float inv = 1.f / (lac + 1e-16f);
        float4 w0 = {ac[0] * inv, ac[1] * inv, ac[2] * inv, ac[3] * inv};
        float4 w1 = {ac[4] * inv, ac[5] * inv, ac[6] * inv, ac[7] * inv};
        float* o = oslice + ((size_t)y * NNODES + i) * HIDDIM + 8 * s;
        *(float4*)o = w0;
        *(float4*)(o + 4) = w1;
    }
}

// ---------------- beta gate layer 3 (head mean over 8 slices) ----------------
__global__ __launch_bounds__(128) void beta3_kernel(const float* __restrict__ obuf8,
                                                    const float* __restrict__ s,
                                                    const float* __restrict__ Wb,
                                                    float* __restrict__ out) {
    int i = blockIdx.x, t = threadIdx.x;
    float o = 0.f;
#pragma unroll
    for (int y = 0; y < 8; ++y) o += obuf8[((size_t)y * NNODES + i) * HIDDIM + t];
    o *= 0.125f;
    float r = s[(size_t)i * HIDDIM + t];
    float part = o * Wb[t] + r * Wb[128 + t] + (o - r) * Wb[256 + t];
#pragma unroll
    for (int msk = 1; msk <= 32; msk <<= 1) part += __shfl_xor(part, msk);
    __shared__ float wsum[2];
    if ((t & 63) == 0) wsum[t >> 6] = part;
    __syncthreads();
    float tot = wsum[0] + wsum[1];
    float g = 1.f / (1.f + __expf(-tot));
    out[(size_t)i * HIDDIM + t] = g * r + (1.f - g) * o;
}

// ---------------- batchnorm ----------------
__global__ __launch_bounds__(128) void bn_stats_kernel(const float* __restrict__ x,
                                                       float* __restrict__ stat, int n) {
    int t = threadIdx.x;
    float s = 0.f, sq = 0.f;
    for (int i = blockIdx.x; i < n; i += gridDim.x) {
        float v = x[(size_t)i * HIDDIM + t];
        s += v;
        sq += v * v;
    }
    atomicAdd(&stat[t], s);
    atomicAdd(&stat[HIDDIM + t], sq);
}

__global__ __launch_bounds__(128) void bn_apply_kernel(float* __restrict__ x,
                                                       const float* __restrict__ stat,
                                                       const float* __restrict__ gamma,
                                                       const float* __restrict__ beta, int n,
                                                       unsigned short* __restrict__ cat) {
    int t = threadIdx.x;
    float mu = stat[t] / (float)n;
    float var = stat[HIDDIM + t] / (float)n - mu * mu;
    float rs = rsqrtf(var + 1e-5f);
    float g = gamma[t], b = beta[t];
    for (int i = blockIdx.x; i < n; i += gridDim.x) {
        float v = x[(size_t)i * HIDDIM + t];
        v = fmaxf((v - mu) * rs * g + b, 0.f);
        x[(size_t)i * HIDDIM + t] = v;
        if (cat) {
            unsigned short hi = f2bf(v);
            unsigned short lo = f2bf(v - bf2f(hi));
            unsigned short* row = cat + (size_t)i * KC;
            row[t] = hi;
            row[128 + t] = lo;
            row[256 + t] = hi;
        }
    }
}

// ---------------- pool ----------------
__global__ __launch_bounds__(256) void gb_kernel(const int* __restrict__ batch,
                                                 int* __restrict__ gs,
                                                 int* __restrict__ ge, int n) {
    int i = blockIdx.x * 256 + threadIdx.x;
    if (i >= n) return;
    int b = batch[i];
    if (i == 0 || batch[i - 1] != b) gs[b] = i;
    if (i == n - 1 || batch[i + 1] != b) ge[b] = i + 1;
}

__global__ __launch_bounds__(256) void pool_part_kernel(const float* __restrict__ x,
                                                        const int* __restrict__ gs,
                                                        const int* __restrict__ ge,
                                                        float* __restrict__ out) {
    int g = blockIdx.x, c = blockIdx.y;
    int t = threadIdx.x;
    int f = t & 127, half = t >> 7;
    int s = gs[g], e = ge[g];
    float acc = 0.f;
    for (int i = s + 2 * c + half; i < e; i += 16) acc += x[(size_t)i * HIDDIM + f];
    __shared__ float l0[128];
    if (half == 0) l0[f] = acc;
    __syncthreads();
    if (half == 1) atomicAdd(&out[g * HIDDIM + f], l0[f] + acc);
}

__global__ __launch_bounds__(128) void pool_div_kernel(float* __restrict__ out,
                                                       const int* __restrict__ gs,
                                                       const int* __restrict__ ge) {
    int g = blockIdx.x, t = threadIdx.x;
    int c = ge[g] - gs[g];
    out[g * HIDDIM + t] /= (float)(c > 0 ? c : 1);
}

// ---------------- host ----------------
extern "C" void kernel_launch(void* const* d_in, const int* in_sizes, int n_in,
                              void* d_out, int out_size, void* d_ws, size_t ws_size,
                              hipStream_t stream) {
    const float* x       = (const float*)d_in[0];
    const int*   ei      = (const int*)d_in[1];
    const int*   batch   = (const int*)d_in[2];
    const float* Wp      = (const float*)d_in[3];
    const float* bp      = (const float*)d_in[4];
    const float* Wq      = (const float*)d_in[5];
    const float* bq      = (const float*)d_in[6];
    const float* Wk      = (const float*)d_in[7];
    const float* bk      = (const float*)d_in[8];
    const float* Wv      = (const float*)d_in[9];
    const float* bv      = (const float*)d_in[10];
    const float* Ws      = (const float*)d_in[11];
    const float* bs      = (const float*)d_in[12];
    const float* Wbeta   = (const float*)d_in[13];
    const float* Wq3     = (const float*)d_in[14];
    const float* bq3     = (const float*)d_in[15];
    const float* Wk3     = (const float*)d_in[16];
    const float* bk3     = (const float*)d_in[17];
    const float* Wv3     = (const float*)d_in[18];
    const float* bv3     = (const float*)d_in[19];
    const float* Ws3     = (const float*)d_in[20];
    const float* bs3     = (const float*)d_in[21];
    const float* Wbeta3  = (const float*)d_in[22];
    const float* bn_gamma = (const float*)d_in[23];
    const float* bn_beta  = (const float*)d_in[24];
    float* out = (float*)d_out;

    const int* esrc = ei;
    const int* edst = ei + NEDGES;

    char* wpc = (char*)d_ws;
    auto alloc = [&](size_t nbytes) -> char* {
        char* p = wpc;
        wpc += (nbytes + 255) & ~(size_t)255;
        return p;
    };
    unsigned short* Acat  = (unsigned short*)alloc((size_t)NPAD * KC * 2);
    unsigned short* WtAll = (unsigned short*)alloc((size_t)4864 * KC * 2);
    float* bcat   = (float*)alloc(4608 * 4);
    float* qsbuf  = (float*)alloc((size_t)NNODES * 512 * 4);   // qs fp32 / q3 bf16 alias
    unsigned short* kvbuf = (unsigned short*)alloc((size_t)NNODES * 1024 * 2);
    float* obuf8  = (float*)alloc((size_t)8 * NNODES * HIDDIM * 4);
    float* hbuf   = (float*)alloc((size_t)NNODES * HIDDIM * 4);
    float* obuf   = (float*)alloc((size_t)NNODES * HIDDIM * 4);
    float* sb     = (float*)alloc((size_t)NNODES * HIDDIM * 4);
    int*   deg    = (int*)alloc((2 * NNODES + 128 + 4 * 256) * 4);
    int*   cursor = deg + NNODES;
    int*   gs     = deg + 2 * NNODES;
    int*   ge     = gs + NGRAPH;
    float* bnstat4 = (float*)(deg + 2 * NNODES + 128);
    int*   chunk  = (int*)alloc(NNODES * 4);
    int*   bsum   = (int*)alloc(128 * 4);
    int*   offs   = (int*)alloc((NNODES + 1) * 4);
    int*   csrsrc = (int*)alloc(NEDGES * 4);

    unsigned short* WtL   = WtAll;
    unsigned short* Wpt   = WtAll + (size_t)1536 * KC;
    unsigned short* Ws3t  = WtAll + (size_t)1664 * KC;
    unsigned short* Wt3q  = WtAll + (size_t)1792 * KC;
    unsigned short* Wt3kv = WtAll + (size_t)2816 * KC;
    float* bcatL = bcat;
    float* b3q   = bcat + 1536;
    float* b3kv  = bcat + 2560;
    unsigned short* q3buf = (unsigned short*)qsbuf;  // [N][512] bf16

    const int TB = 256;
    const int ZWORDS = 2 * NNODES + 128 + 4 * 256;
    zero_kernel<<<(ZWORDS + TB - 1) / TB, TB, 0, stream>>>((float*)deg, ZWORDS);
    count_deg_kernel<<<(NEDGES + TB - 1) / TB, TB, 0, stream>>>(edst, deg, NEDGES);
    const int NB = (NNODES + 255) / 256;
    scan1_kernel<<<NB, 256, 0, stream>>>(deg, chunk, bsum, NNODES);
    scan2_kernel<<<1, 128, 0, stream>>>(bsum, NB);
    scan3_kernel<<<NB, 256, 0, stream>>>(chunk, bsum, offs, NNODES);
    scatter_kernel<<<(NEDGES + TB - 1) / TB, TB, 0, stream>>>(esrc, edst, offs, cursor, csrsrc, NEDGES);
    gb_kernel<<<(NNODES + TB - 1) / TB, TB, 0, stream>>>(batch, gs, ge, NNODES);

    prep_w_kernel<<<4864, 128, 0, stream>>>(Wq, Wk, Wv, Ws, Wp, Ws3, Wq3, Wk3, Wv3, WtAll);
    prep_bias_kernel<<<(4608 + TB - 1) / TB, TB, 0, stream>>>(bq, bk, bv, bs, bq3, bk3, bv3, bcat);

    const int CATB = (NPAD * HIDDIM + TB - 1) / TB;
    const int GSW = 8 * ((GXTILES + 7) / 8);  // 160 swizzled x-slots

    cat_from_kernel<<<CATB, TB, 0, stream>>>(x, Acat);
    gemm_mfma_kernel<float, 12, 1><<<GSW * 1, 256, 0, stream>>>(Acat, Wpt, bp, hbuf, 128, NNODES);
    cat_from_kernel<<<CATB, TB, 0, stream>>>(hbuf, Acat);

    for (int li = 0; li < 3; ++li) {
        const unsigned short* Wl = WtL + (size_t)li * 512 * KC;
        gemm_mfma_kernel<float, 12, 2><<<GSW * 2, 256, 0, stream>>>(
            Acat, Wl, bcatL + li * 512, qsbuf, 256, NNODES);
        gemm_mfma_kernel<unsigned short, 8, 2><<<GSW * 2, 256, 0, stream>>>(
            Acat, Wl + (size_t)256 * KC, bcatL + li * 512 + 256, kvbuf, 256, NNODES);
        attn_small_kernel<<<NNODES, 64, 0, stream>>>(qsbuf, kvbuf, Wbeta + li * 384,
                                                     offs, csrsrc, obuf);
        float* st = bnstat4 + li * 256;
        bn_stats_kernel<<<640, 128, 0, stream>>>(obuf, st, NNODES);
        bn_apply_kernel<<<512, 128, 0, stream>>>(obuf, st, bn_gamma + li * HIDDIM,
                                                 bn_beta + li * HIDDIM, NNODES, Acat);
    }

    for (int h2 = 0; h2 < 2; ++h2) {
        gemm_mfma_kernel<unsigned short, 8, 4><<<GSW * 4, 256, 0, stream>>>(
            Acat, Wt3q + (size_t)h2 * 512 * KC, b3q + h2 * 512, q3buf, 512, NNODES);
        gemm_mfma_kernel<unsigned short, 8, 8><<<GSW * 8, 256, 0, stream>>>(
            Acat, Wt3kv + (size_t)h2 * 1024 * KC, b3kv + h2 * 1024, kvbuf, 1024, NNODES);
        attn_big_kernel<<<dim3(NNODES, 4), 64, 0, stream>>>(
            q3buf, kvbuf, offs, csrsrc, obuf8 + (size_t)h2 * 4 * NNODES * HIDDIM);
    }
    gemm_mfma_kernel<float, 12, 1><<<GSW * 1, 256, 0, stream>>>(Acat, Ws3t, bs3, sb, 128, NNODES);
    beta3_kernel<<<NNODES, 128, 0, stream>>>(obuf8, sb, Wbeta3, hbuf);
    float* st3 = bnstat4 + 3 * 256;
    bn_stats_kernel<<<640, 128, 0, stream>>>(hbuf, st3, NNODES);
    bn_apply_kernel<<<512, 128, 0, stream>>>(hbuf, st3, bn_gamma + 3 * HIDDIM,
                                             bn_beta + 3 * HIDDIM, NNODES, (unsigned short*)0);

    zero_kernel<<<(NGRAPH * HIDDIM + TB - 1) / TB, TB, 0, stream>>>(out, NGRAPH * HIDDIM);
    pool_part_kernel<<<dim3(NGRAPH, 8), 256, 0, stream>>>(hbuf, gs, ge, out);
    pool_div_kernel<<<NGRAPH, 128, 0, stream>>>(out, gs, ge);
}

// Round 11
// 807.886 us; speedup vs baseline: 1.0297x; 1.0297x over previous
//
#include <hip/hip_runtime.h>
#include <math.h>

#define NNODES 20000
#define NPAD   20096   // 157 * 128
#define NEDGES 160000
#define HIDDIM 128
#define NHEADS 8
#define NGRAPH 64
#define KC 384   // concatenated K (hi | lo | hi)
#define GXTILES 157

typedef short short8 __attribute__((ext_vector_type(8)));
typedef float floatx4 __attribute__((ext_vector_type(4)));
typedef unsigned short ushort4v __attribute__((ext_vector_type(4)));

__device__ inline unsigned short f2bf(float x) {
    unsigned u = __float_as_uint(x);
    u += 0x7fff + ((u >> 16) & 1);
    return (unsigned short)(u >> 16);
}
__device__ inline float bf2f(unsigned short h) {
    return __uint_as_float(((unsigned)h) << 16);
}

// ---------------- utility ----------------
__global__ __launch_bounds__(256) void zero_kernel(float* __restrict__ p, int n) {
    int i = blockIdx.x * blockDim.x + threadIdx.x;
    if (i < n) p[i] = 0.f;
}

// ---------------- CSR build ----------------
__global__ __launch_bounds__(256) void count_deg_kernel(const int* __restrict__ dst,
                                                        int* __restrict__ deg, int e) {
    int i = blockIdx.x * blockDim.x + threadIdx.x;
    if (i < e) atomicAdd(&deg[dst[i]], 1);
}

__global__ __launch_bounds__(256) void scan1_kernel(const int* __restrict__ deg,
                                                    int* __restrict__ chunk,
                                                    int* __restrict__ bsum, int n) {
    __shared__ int buf[256];
    int t = threadIdx.x;
    int i = blockIdx.x * 256 + t;
    int v = (i < n) ? deg[i] : 0;
    buf[t] = v;
    __syncthreads();
    for (int off = 1; off < 256; off <<= 1) {
        int tmp = (t >= off) ? buf[t - off] : 0;
        __syncthreads();
        buf[t] += tmp;
        __syncthreads();
    }
    if (i < n) chunk[i] = buf[t];
    if (t == 255) bsum[blockIdx.x] = buf[255];
}

__global__ __launch_bounds__(128) void scan2_kernel(int* __restrict__ bsum, int nb) {
    __shared__ int buf[128];
    int t = threadIdx.x;
    int v = (t < nb) ? bsum[t] : 0;
    buf[t] = v;
    __syncthreads();
    for (int off = 1; off < 128; off <<= 1) {
        int tmp = (t >= off) ? buf[t - off] : 0;
        __syncthreads();
        buf[t] += tmp;
        __syncthreads();
    }
    if (t < nb) bsum[t] = buf[t] - v;
}

__global__ __launch_bounds__(256) void scan3_kernel(const int* __restrict__ chunk,
                                                    const int* __restrict__ bsum,
                                                    int* __restrict__ offs, int n) {
    int i = blockIdx.x * 256 + threadIdx.x;
    if (i < n) offs[i + 1] = chunk[i] + bsum[i >> 8];
    if (i == 0) offs[0] = 0;
}

__global__ __launch_bounds__(256) void scatter_kernel(const int* __restrict__ src,
                                                      const int* __restrict__ dst,
                                                      const int* __restrict__ offs,
                                                      int* __restrict__ cursor,
                                                      int* __restrict__ csr_src, int e) {
    int i = blockIdx.x * blockDim.x + threadIdx.x;
    if (i < e) {
        int d = dst[i];
        int pos = offs[d] + atomicAdd(&cursor[d], 1);
        csr_src[pos] = src[i];
    }
}

// ---------------- weight prep ----------------
__global__ __launch_bounds__(128) void prep_w_kernel(
    const float* __restrict__ Wq, const float* __restrict__ Wk,
    const float* __restrict__ Wv, const float* __restrict__ Ws,
    const float* __restrict__ Wp, const float* __restrict__ Ws3,
    const float* __restrict__ Wq3, const float* __restrict__ Wk3,
    const float* __restrict__ Wv3, unsigned short* __restrict__ WtAll) {
    int id = blockIdx.x;
    int k = threadIdx.x;
    float w;
    if (id < 1536) {
        int li = id / 512, n = id % 512, sel = n >> 7, np = n & 127;
        const float* W = (sel == 0) ? Wq : (sel == 1) ? Ws : (sel == 2) ? Wk : Wv;
        w = W[li * 16384 + k * 128 + np];
    } else if (id < 1664) {
        w = Wp[k * 128 + (id - 1536)];
    } else if (id < 1792) {
        w = Ws3[k * 128 + (id - 1664)];
    } else if (id < 2816) {
        int r = id - 1792, h = r >> 7, j = r & 127;
        w = Wq3[k * 1024 + h * 128 + j];
    } else {
        int r = id - 2816, h = r >> 8, jj = r & 255;
        const float* W = (jj < 128) ? Wk3 : Wv3;
        w = W[k * 1024 + h * 128 + (jj & 127)];
    }
    unsigned short hi = f2bf(w);
    unsigned short lo = f2bf(w - bf2f(hi));
    unsigned short* dst = WtAll + (size_t)id * KC;
    dst[k] = hi;
    dst[128 + k] = hi;
    dst[256 + k] = lo;
}

__global__ __launch_bounds__(256) void prep_bias_kernel(
    const float* __restrict__ bq, const float* __restrict__ bk,
    const float* __restrict__ bv, const float* __restrict__ bs,
    const float* __restrict__ bq3, const float* __restrict__ bk3,
    const float* __restrict__ bv3, float* __restrict__ bcat) {
    int id = blockIdx.x * 256 + threadIdx.x;
    if (id >= 4608) return;
    float v;
    if (id < 1536) {
        int li = id / 512, n = id % 512, sel = n >> 7, np = n & 127;
        const float* b = (sel == 0) ? bq : (sel == 1) ? bs : (sel == 2) ? bk : bv;
        v = b[li * 128 + np];
    } else if (id < 2560) {
        v = bq3[id - 1536];
    } else {
        int r = id - 2560, h = r >> 8, jj = r & 255;
        const float* b = (jj < 128) ? bk3 : bv3;
        v = b[h * 128 + (jj & 127)];
    }
    bcat[id] = v;
}

// ---------------- activation -> split-bf16 A_cat ----------------
__global__ __launch_bounds__(256) void cat_from_kernel(const float* __restrict__ h,
                                                       unsigned short* __restrict__ Acat) {
    int idx = blockIdx.x * 256 + threadIdx.x;
    if (idx >= NPAD * HIDDIM) return;
    int r = idx >> 7, k = idx & 127;
    float x = (r < NNODES) ? h[idx] : 0.f;
    unsigned short hi = f2bf(x);
    unsigned short lo = f2bf(x - bf2f(hi));
    unsigned short* row = Acat + (size_t)r * KC;
    row[k] = hi;
    row[128 + k] = lo;
    row[256 + k] = hi;
}

// ---------------- MFMA GEMM: XCD swizzle + swizzled-LDS coalesced epilogue ----------------
// 1-D grid of 160*BY blocks; xcd = id&7, bx = (idx/BY)*8+xcd, by = idx%BY: all
// column passes of an A stripe stay on one XCD (A L2-resident; FETCH ~logical).
// Epilogue: acc -> LDS with XOR-swizzled 16B chunks (bank-floor, no excess
// conflicts), then 16 lanes copy each 256B/512B node row CONTIGUOUSLY to global
// (full-line writes). Two node-half phases; LDS 16 KB (bf16) / 32 KB (fp32).
template <typename OutT, int KG, int BY>
__global__ __launch_bounds__(256) void gemm_mfma_kernel(
    const unsigned short* __restrict__ Acat, const unsigned short* __restrict__ Wt,
    const float* __restrict__ bias, OutT* __restrict__ C, int M, int nrows) {
    constexpr int ELEM = sizeof(OutT);
    constexpr int ROWB = 128 * ELEM;     // bytes per node row in tile: 256 / 512
    constexpr int NCH  = ROWB / 16;      // 16B chunks per row: 16 / 32
    __shared__ char Cs[64 * ROWB];
    int id = blockIdx.x;
    int xcd = id & 7;
    int idx = id >> 3;
    int bx = (idx / BY) * 8 + xcd;
    int by = idx % BY;
    if (bx >= GXTILES) return;
    int tt = threadIdx.x;
    int lane = tt & 63;
    int wave = tt >> 6;
    int nodeBase = bx * 128 + (wave & 1) * 64;
    int featLoc = (wave >> 1) * 64;
    int featBase = by * 128 + featLoc;
    int m = lane & 15;
    int q = lane >> 4;
    int ko = q * 8;
    const unsigned short* wptr = Wt + (size_t)(featBase + m) * KC + ko;    // A operand
    const unsigned short* aptr = Acat + (size_t)(nodeBase + m) * KC + ko;  // B operand
    floatx4 acc[4][4];  // [feat tile r][node tile c]
#pragma unroll
    for (int r = 0; r < 4; ++r)
#pragma unroll
        for (int c = 0; c < 4; ++c) acc[r][c] = (floatx4){0.f, 0.f, 0.f, 0.f};
#pragma unroll
    for (int kg = 0; kg < KG; ++kg) {
        short8 a[4], b[4];
#pragma unroll
        for (int r = 0; r < 4; ++r) a[r] = *(const short8*)(wptr + (size_t)r * 16 * KC + kg * 32);
#pragma unroll
        for (int c = 0; c < 4; ++c) b[c] = *(const short8*)(aptr + (size_t)c * 16 * KC + kg * 32);
#pragma unroll
        for (int r = 0; r < 4; ++r)
#pragma unroll
            for (int c = 0; c < 4; ++c)
                acc[r][c] = __builtin_amdgcn_mfma_f32_16x16x32_bf16(a[r], b[c], acc[r][c], 0, 0, 0);
    }
    // ---- epilogue: two node-half phases through swizzled LDS ----
#pragma unroll
    for (int ph = 0; ph < 2; ++ph) {
        if ((wave & 1) == ph) {
#pragma unroll
            for (int r = 0; r < 4; ++r) {
                int fl = featLoc + r * 16 + q * 4;  // feature offset in 128-tile
                float4 bv = *(const float4*)(bias + by * 128 + fl);
#pragma unroll
                for (int c = 0; c < 4; ++c) {
                    int row = c * 16 + m;  // local node 0..63
                    float v0 = acc[r][c][0] + bv.x;
                    float v1 = acc[r][c][1] + bv.y;
                    float v2 = acc[r][c][2] + bv.z;
                    float v3 = acc[r][c][3] + bv.w;
                    if (ELEM == 2) {
                        int chunk = fl >> 3;
                        int addr = row * ROWB + ((chunk ^ (row & (NCH - 1))) << 4) + (fl & 7) * 2;
                        ushort4v o = {f2bf(v0), f2bf(v1), f2bf(v2), f2bf(v3)};
                        *(ushort4v*)(Cs + addr) = o;
                    } else {
                        int chunk = fl >> 2;
                        int addr = row * ROWB + ((chunk ^ (row & (NCH - 1))) << 4);
                        float4 o = {v0, v1, v2, v3};
                        *(float4*)(Cs + addr) = o;
                    }
                }
            }
        }
        __syncthreads();
        if (ELEM == 2) {
#pragma unroll
            for (int it = 0; it < 4; ++it) {
                int row = it * 16 + wave * 4 + (lane >> 4);
                int c = lane & 15;
                int nodeG = bx * 128 + ph * 64 + row;
                if (nodeG < nrows) {
                    const uint4* src = (const uint4*)(Cs + row * ROWB + ((c ^ (row & 15)) << 4));
                    uint4* dst = (uint4*)((char*)C + ((size_t)nodeG * M + by * 128) * 2 + c * 16);
                    *dst = *src;
                }
            }
        } else {
#pragma unroll
            for (int it = 0; it < 8; ++it) {
                int row = it * 8 + wave * 2 + (lane >> 5);
                int c = lane & 31;
                int nodeG = bx * 128 + ph * 64 + row;
                if (nodeG < nrows) {
                    const uint4* src = (const uint4*)(Cs + row * ROWB + ((c ^ (row & 31)) << 4));
                    uint4* dst = (uint4*)((char*)C + ((size_t)nodeG * M + by * 128) * 4 + c * 16);
                    *dst = *src;
                }
            }
        }
        __syncthreads();
    }
}

// ---------------- attention layers 0-2: 2 edge slots x (8 heads x 4 lanes) ----------------
__global__ __launch_bounds__(64) void attn_small_kernel(
    const float* __restrict__ qs, const unsigned short* __restrict__ kv,
    const float* __restrict__ Wb,
    const int* __restrict__ offs, const int* __restrict__ csr_src,
    float* __restrict__ out) {
    int i = blockIdx.x;
    int l = threadIdx.x;
    int g = l >> 5;
    int d0 = (l & 31) * 4;
    float4 qv = *(const float4*)(qs + (size_t)i * 256 + d0);
    int e0 = offs[i], e1 = offs[i + 1];
    float mm = -1e30f, lac = 0.f;
    float a0 = 0.f, a1 = 0.f, a2 = 0.f, a3 = 0.f;
    for (int e = e0 + g; e < e1; e += 2) {
        int sn = csr_src[e];
        const unsigned short* row = kv + (size_t)sn * 256;
        uint2 kk = *(const uint2*)(row + d0);
        uint2 vv = *(const uint2*)(row + 128 + d0);
        float k0 = bf2f((unsigned short)(kk.x & 0xffff)), k1 = bf2f((unsigned short)(kk.x >> 16));
        float k2 = bf2f((unsigned short)(kk.y & 0xffff)), k3 = bf2f((unsigned short)(kk.y >> 16));
        float p = qv.x * k0 + qv.y * k1 + qv.z * k2 + qv.w * k3;
        p += __shfl_xor(p, 1);
        p += __shfl_xor(p, 2);
        float logit = p * 0.25f;
        float mnew = fmaxf(mm, logit);
        float sc = __expf(mm - mnew);
        float w = __expf(logit - mnew);
        float v0 = bf2f((unsigned short)(vv.x & 0xffff)), v1 = bf2f((unsigned short)(vv.x >> 16));
        float v2 = bf2f((unsigned short)(vv.y & 0xffff)), v3 = bf2f((unsigned short)(vv.y >> 16));
        a0 = a0 * sc + w * v0;
        a1 = a1 * sc + w * v1;
        a2 = a2 * sc + w * v2;
        a3 = a3 * sc + w * v3;
        lac = lac * sc + w;
        mm = mnew;
    }
    float mo = __shfl_xor(mm, 32), lo = __shfl_xor(lac, 32);
    float b0 = __shfl_xor(a0, 32), b1 = __shfl_xor(a1, 32);
    float b2 = __shfl_xor(a2, 32), b3 = __shfl_xor(a3, 32);
    float ms = fmaxf(mm, mo);
    float s0 = __expf(mm - ms), s1 = __expf(mo - ms);
    a0 = a0 * s0 + b0 * s1;
    a1 = a1 * s0 + b1 * s1;
    a2 = a2 * s0 + b2 * s1;
    a3 = a3 * s0 + b3 * s1;
    lac = lac * s0 + lo * s1;
    float inv = 1.f / (lac + 1e-16f);
    float o0 = a0 * inv, o1 = a1 * inv, o2 = a2 * inv, o3 = a3 * inv;
    float4 rv = *(const float4*)(qs + (size_t)i * 256 + 128 + d0);
    float part = o0 * Wb[d0] + o1 * Wb[d0 + 1] + o2 * Wb[d0 + 2] + o3 * Wb[d0 + 3]
               + rv.x * Wb[128 + d0] + rv.y * Wb[128 + d0 + 1]
               + rv.z * Wb[128 + d0 + 2] + rv.w * Wb[128 + d0 + 3]
               + (o0 - rv.x) * Wb[256 + d0] + (o1 - rv.y) * Wb[256 + d0 + 1]
               + (o2 - rv.z) * Wb[256 + d0 + 2] + (o3 - rv.w) * Wb[256 + d0 + 3];
    if (g) part = 0.f;
#pragma unroll
    for (int msk = 1; msk <= 32; msk <<= 1) part += __shfl_xor(part, msk);
    float gg = 1.f / (1.f + __expf(-part));
    if (g == 0) {
        float4 o4 = {gg * rv.x + (1.f - gg) * o0, gg * rv.y + (1.f - gg) * o1,
                     gg * rv.z + (1.f - gg) * o2, gg * rv.w + (1.f - gg) * o3};
        *(float4*)(out + (size_t)i * HIDDIM + d0) = o4;
    }
}

// ---------------- attention layer 3: 4 edge slots x 16 lanes x 8 dims ----------------
__global__ __launch_bounds__(64) void attn_big_kernel(
    const unsigned short* __restrict__ q3, const unsigned short* __restrict__ kv3,
    const int* __restrict__ offs, const int* __restrict__ csr_src,
    float* __restrict__ oslice) {
    int i = blockIdx.x;
    int y = blockIdx.y;
    int l = threadIdx.x;
    int g = l >> 4;
    int s = l & 15;
    uint4 qq = *(const uint4*)(q3 + (size_t)i * 512 + y * 128 + 8 * s);
    float q0 = bf2f((unsigned short)(qq.x & 0xffff)), q1 = bf2f((unsigned short)(qq.x >> 16));
    float q2 = bf2f((unsigned short)(qq.y & 0xffff)), q3f = bf2f((unsigned short)(qq.y >> 16));
    float q4 = bf2f((unsigned short)(qq.z & 0xffff)), q5 = bf2f((unsigned short)(qq.z >> 16));
    float q6 = bf2f((unsigned short)(qq.w & 0xffff)), q7 = bf2f((unsigned short)(qq.w >> 16));
    int e0 = offs[i], e1 = offs[i + 1];
    float mm = -1e30f, lac = 0.f;
    float ac[8];
#pragma unroll
    for (int j = 0; j < 8; ++j) ac[j] = 0.f;
    for (int e = e0 + g; e < e1; e += 4) {
        int sn = csr_src[e];
        const unsigned short* row = kv3 + (size_t)sn * 1024 + y * 256 + 8 * s;
        uint4 kk = *(const uint4*)row;
        uint4 vv = *(const uint4*)(row + 128);
        float k0 = bf2f((unsigned short)(kk.x & 0xffff)), k1 = bf2f((unsigned short)(kk.x >> 16));
        float k2 = bf2f((unsigned short)(kk.y & 0xffff)), k3 = bf2f((unsigned short)(kk.y >> 16));
        float k4 = bf2f((unsigned short)(kk.z & 0xffff)), k5 = bf2f((unsigned short)(kk.z >> 16));
        float k6 = bf2f((unsigned short)(kk.w & 0xffff)), k7 = bf2f((unsigned short)(kk.w >> 16));
        float p = q0 * k0 + q1 * k1 + q2 * k2 + q3f * k3
                + q4 * k4 + q5 * k5 + q6 * k6 + q7 * k7;
        p += __shfl_xor(p, 1);
        p += __shfl_xor(p, 2);
        p += __shfl_xor(p, 4);
        p += __shfl_xor(p, 8);
        float logit = p * 0.08838834764831845f;
        float mnew = fmaxf(mm, logit);
        float sc = __expf(mm - mnew);
        float w = __expf(logit - mnew);
        float v0 = bf2f((unsigned short)(vv.x & 0xffff)), v1 = bf2f((unsigned short)(vv.x >> 16));
        float v2 = bf2f((unsigned short)(vv.y & 0xffff)), v3 = bf2f((unsigned short)(vv.y >> 16));
        float v4 = bf2f((unsigned short)(vv.z & 0xffff)), v5 = bf2f((unsigned short)(vv.z >> 16));
        float v6 = bf2f((unsigned short)(vv.w & 0xffff)), v7 = bf2f((unsigned short)(vv.w >> 16));
        ac[0] = ac[0] * sc + w * v0; ac[1] = ac[1] * sc + w * v1;
        ac[2] = ac[2] * sc + w * v2; ac[3] = ac[3] * sc + w * v3;
        ac[4] = ac[4] * sc + w * v4; ac[5] = ac[5] * sc + w * v5;
        ac[6] = ac[6] * sc + w * v6; ac[7] = ac[7] * sc + w * v7;
        lac = lac * sc + w;
        mm = mnew;
    }
#pragma unroll
    for (int msk = 16; msk <= 32; msk <<= 1) {
        float mo = __shfl_xor(mm, msk), lo = __shfl_xor(lac, msk);
        float bo[8];
#pragma unroll
        for (int j = 0; j < 8; ++j) bo[j] = __shfl_xor(ac[j], msk);
        float ms = fmaxf(mm, mo);
        float s0 = __expf(mm - ms), s1 = __expf(mo - ms);
#pragma unroll
        for (int j = 0; j < 8; ++j) ac[j] = ac[j] * s0 + bo[j] * s1;
        lac = lac * s0 + lo * s1;
        mm = ms;
    }
    if (g == 0) {
        float inv = 1.f / (lac + 1e-16f);
        float4 w0 = {ac[0] * inv, ac[1] * inv, ac[2] * inv, ac[3] * inv};
        float4 w1 = {ac[4] * inv, ac[5] * inv, ac[6] * inv, ac[7] * inv};
        float* o = oslice + ((size_t)y * NNODES + i) * HIDDIM + 8 * s;
        *(float4*)o = w0;
        *(float4*)(o + 4) = w1;
    }
}

// ---------------- beta gate layer 3 (head mean over 8 slices) ----------------
__global__ __launch_bounds__(128) void beta3_kernel(const float* __restrict__ obuf8,
                                                    const float* __restrict__ s,
                                                    const float* __restrict__ Wb,
                                                    float* __restrict__ out) {
    int i = blockIdx.x, t = threadIdx.x;
    float o = 0.f;
#pragma unroll
    for (int y = 0; y < 8; ++y) o += obuf8[((size_t)y * NNODES + i) * HIDDIM + t];
    o *= 0.125f;
    float r = s[(size_t)i * HIDDIM + t];
    float part = o * Wb[t] + r * Wb[128 + t] + (o - r) * Wb[256 + t];
#pragma unroll
    for (int msk = 1; msk <= 32; msk <<= 1) part += __shfl_xor(part, msk);
    __shared__ float wsum[2];
    if ((t & 63) == 0) wsum[t >> 6] = part;
    __syncthreads();
    float tot = wsum[0] + wsum[1];
    float g = 1.f / (1.f + __expf(-tot));
    out[(size_t)i * HIDDIM + t] = g * r + (1.f - g) * o;
}

// ---------------- batchnorm ----------------
__global__ __launch_bounds__(128) void bn_stats_kernel(const float* __restrict__ x,
                                                       float* __restrict__ stat, int n) {
    int t = threadIdx.x;
    float s = 0.f, sq = 0.f;
    for (int i = blockIdx.x; i < n; i += gridDim.x) {
        float v = x[(size_t)i * HIDDIM + t];
        s += v;
        sq += v * v;
    }
    atomicAdd(&stat[t], s);
    atomicAdd(&stat[HIDDIM + t], sq);
}

__global__ __launch_bounds__(128) void bn_apply_kernel(float* __restrict__ x,
                                                       const float* __restrict__ stat,
                                                       const float* __restrict__ gamma,
                                                       const float* __restrict__ beta, int n,
                                                       unsigned short* __restrict__ cat) {
    int t = threadIdx.x;
    float mu = stat[t] / (float)n;
    float var = stat[HIDDIM + t] / (float)n - mu * mu;
    float rs = rsqrtf(var + 1e-5f);
    float g = gamma[t], b = beta[t];
    for (int i = blockIdx.x; i < n; i += gridDim.x) {
        float v = x[(size_t)i * HIDDIM + t];
        v = fmaxf((v - mu) * rs * g + b, 0.f);
        x[(size_t)i * HIDDIM + t] = v;
        if (cat) {
            unsigned short hi = f2bf(v);
            unsigned short lo = f2bf(v - bf2f(hi));
            unsigned short* row = cat + (size_t)i * KC;
            row[t] = hi;
            row[128 + t] = lo;
            row[256 + t] = hi;
        }
    }
}

// ---------------- pool ----------------
__global__ __launch_bounds__(256) void gb_kernel(const int* __restrict__ batch,
                                                 int* __restrict__ gs,
                                                 int* __restrict__ ge, int n) {
    int i = blockIdx.x * 256 + threadIdx.x;
    if (i >= n) return;
    int b = batch[i];
    if (i == 0 || batch[i - 1] != b) gs[b] = i;
    if (i == n - 1 || batch[i + 1] != b) ge[b] = i + 1;
}

__global__ __launch_bounds__(256) void pool_part_kernel(const float* __restrict__ x,
                                                        const int* __restrict__ gs,
                                                        const int* __restrict__ ge,
                                                        float* __restrict__ out) {
    int g = blockIdx.x, c = blockIdx.y;
    int t = threadIdx.x;
    int f = t & 127, half = t >> 7;
    int s = gs[g], e = ge[g];
    float acc = 0.f;
    for (int i = s + 2 * c + half; i < e; i += 16) acc += x[(size_t)i * HIDDIM + f];
    __shared__ float l0[128];
    if (half == 0) l0[f] = acc;
    __syncthreads();
    if (half == 1) atomicAdd(&out[g * HIDDIM + f], l0[f] + acc);
}

__global__ __launch_bounds__(128) void pool_div_kernel(float* __restrict__ out,
                                                       const int* __restrict__ gs,
                                                       const int* __restrict__ ge) {
    int g = blockIdx.x, t = threadIdx.x;
    int c = ge[g] - gs[g];
    out[g * HIDDIM + t] /= (float)(c > 0 ? c : 1);
}

// ---------------- host ----------------
extern "C" void kernel_launch(void* const* d_in, const int* in_sizes, int n_in,
                              void* d_out, int out_size, void* d_ws, size_t ws_size,
                              hipStream_t stream) {
    const float* x       = (const float*)d_in[0];
    const int*   ei      = (const int*)d_in[1];
    const int*   batch   = (const int*)d_in[2];
    const float* Wp      = (const float*)d_in[3];
    const float* bp      = (const float*)d_in[4];
    const float* Wq      = (const float*)d_in[5];
    const float* bq      = (const float*)d_in[6];
    const float* Wk      = (const float*)d_in[7];
    const float* bk      = (const float*)d_in[8];
    const float* Wv      = (const float*)d_in[9];
    const float* bv      = (const float*)d_in[10];
    const float* Ws      = (const float*)d_in[11];
    const float* bs      = (const float*)d_in[12];
    const float* Wbeta   = (const float*)d_in[13];
    const float* Wq3     = (const float*)d_in[14];
    const float* bq3     = (const float*)d_in[15];
    const float* Wk3     = (const float*)d_in[16];
    const float* bk3     = (const float*)d_in[17];
    const float* Wv3     = (const float*)d_in[18];
    const float* bv3     = (const float*)d_in[19];
    const float* Ws3     = (const float*)d_in[20];
    const float* bs3     = (const float*)d_in[21];
    const float* Wbeta3  = (const float*)d_in[22];
    const float* bn_gamma = (const float*)d_in[23];
    const float* bn_beta  = (const float*)d_in[24];
    float* out = (float*)d_out;

    const int* esrc = ei;
    const int* edst = ei + NEDGES;

    char* wpc = (char*)d_ws;
    auto alloc = [&](size_t nbytes) -> char* {
        char* p = wpc;
        wpc += (nbytes + 255) & ~(size_t)255;
        return p;
    };
    unsigned short* Acat  = (unsigned short*)alloc((size_t)NPAD * KC * 2);
    unsigned short* WtAll = (unsigned short*)alloc((size_t)4864 * KC * 2);
    float* bcat   = (float*)alloc(4608 * 4);
    float* qsbuf  = (float*)alloc((size_t)NNODES * 512 * 4);   // qs fp32 / q3 bf16 alias
    unsigned short* kvbuf = (unsigned short*)alloc((size_t)NNODES * 1024 * 2);
    float* obuf8  = (float*)alloc((size_t)8 * NNODES * HIDDIM * 4);
    float* hbuf   = (float*)alloc((size_t)NNODES * HIDDIM * 4);
    float* obuf   = (float*)alloc((size_t)NNODES * HIDDIM * 4);
    float* sb     = (float*)alloc((size_t)NNODES * HIDDIM * 4);
    int*   deg    = (int*)alloc((2 * NNODES + 128 + 4 * 256) * 4);
    int*   cursor = deg + NNODES;
    int*   gs     = deg + 2 * NNODES;
    int*   ge     = gs + NGRAPH;
    float* bnstat4 = (float*)(deg + 2 * NNODES + 128);
    int*   chunk  = (int*)alloc(NNODES * 4);
    int*   bsum   = (int*)alloc(128 * 4);
    int*   offs   = (int*)alloc((NNODES + 1) * 4);
    int*   csrsrc = (int*)alloc(NEDGES * 4);

    unsigned short* WtL   = WtAll;
    unsigned short* Wpt   = WtAll + (size_t)1536 * KC;
    unsigned short* Ws3t  = WtAll + (size_t)1664 * KC;
    unsigned short* Wt3q  = WtAll + (size_t)1792 * KC;
    unsigned short* Wt3kv = WtAll + (size_t)2816 * KC;
    float* bcatL = bcat;
    float* b3q   = bcat + 1536;
    float* b3kv  = bcat + 2560;
    unsigned short* q3buf = (unsigned short*)qsbuf;  // [N][512] bf16

    const int TB = 256;
    const int ZWORDS = 2 * NNODES + 128 + 4 * 256;
    zero_kernel<<<(ZWORDS + TB - 1) / TB, TB, 0, stream>>>((float*)deg, ZWORDS);
    count_deg_kernel<<<(NEDGES + TB - 1) / TB, TB, 0, stream>>>(edst, deg, NEDGES);
    const int NB = (NNODES + 255) / 256;
    scan1_kernel<<<NB, 256, 0, stream>>>(deg, chunk, bsum, NNODES);
    scan2_kernel<<<1, 128, 0, stream>>>(bsum, NB);
    scan3_kernel<<<NB, 256, 0, stream>>>(chunk, bsum, offs, NNODES);
    scatter_kernel<<<(NEDGES + TB - 1) / TB, TB, 0, stream>>>(esrc, edst, offs, cursor, csrsrc, NEDGES);
    gb_kernel<<<(NNODES + TB - 1) / TB, TB, 0, stream>>>(batch, gs, ge, NNODES);

    prep_w_kernel<<<4864, 128, 0, stream>>>(Wq, Wk, Wv, Ws, Wp, Ws3, Wq3, Wk3, Wv3, WtAll);
    prep_bias_kernel<<<(4608 + TB - 1) / TB, TB, 0, stream>>>(bq, bk, bv, bs, bq3, bk3, bv3, bcat);

    const int CATB = (NPAD * HIDDIM + TB - 1) / TB;
    const int GSW = 8 * ((GXTILES + 7) / 8);  // 160 swizzled x-slots

    cat_from_kernel<<<CATB, TB, 0, stream>>>(x, Acat);
    gemm_mfma_kernel<float, 12, 1><<<GSW * 1, 256, 0, stream>>>(Acat, Wpt, bp, hbuf, 128, NNODES);
    cat_from_kernel<<<CATB, TB, 0, stream>>>(hbuf, Acat);

    for (int li = 0; li < 3; ++li) {
        const unsigned short* Wl = WtL + (size_t)li * 512 * KC;
        gemm_mfma_kernel<float, 12, 2><<<GSW * 2, 256, 0, stream>>>(
            Acat, Wl, bcatL + li * 512, qsbuf, 256, NNODES);
        gemm_mfma_kernel<unsigned short, 8, 2><<<GSW * 2, 256, 0, stream>>>(
            Acat, Wl + (size_t)256 * KC, bcatL + li * 512 + 256, kvbuf, 256, NNODES);
        attn_small_kernel<<<NNODES, 64, 0, stream>>>(qsbuf, kvbuf, Wbeta + li * 384,
                                                     offs, csrsrc, obuf);
        float* st = bnstat4 + li * 256;
        bn_stats_kernel<<<640, 128, 0, stream>>>(obuf, st, NNODES);
        bn_apply_kernel<<<512, 128, 0, stream>>>(obuf, st, bn_gamma + li * HIDDIM,
                                                 bn_beta + li * HIDDIM, NNODES, Acat);
    }

    for (int h2 = 0; h2 < 2; ++h2) {
        gemm_mfma_kernel<unsigned short, 8, 4><<<GSW * 4, 256, 0, stream>>>(
            Acat, Wt3q + (size_t)h2 * 512 * KC, b3q + h2 * 512, q3buf, 512, NNODES);
        gemm_mfma_kernel<unsigned short, 8, 8><<<GSW * 8, 256, 0, stream>>>(
            Acat, Wt3kv + (size_t)h2 * 1024 * KC, b3kv + h2 * 1024, kvbuf, 1024, NNODES);
        attn_big_kernel<<<dim3(NNODES, 4), 64, 0, stream>>>(
            q3buf, kvbuf, offs, csrsrc, obuf8 + (size_t)h2 * 4 * NNODES * HIDDIM);
    }
    gemm_mfma_kernel<float, 12, 1><<<GSW * 1, 256, 0, stream>>>(Acat, Ws3t, bs3, sb, 128, NNODES);
    beta3_kernel<<<NNODES, 128, 0, stream>>>(obuf8, sb, Wbeta3, hbuf);
    float* st3 = bnstat4 + 3 * 256;
    bn_stats_kernel<<<640, 128, 0, stream>>>(hbuf, st3, NNODES);
    bn_apply_kernel<<<512, 128, 0, stream>>>(hbuf, st3, bn_gamma + 3 * HIDDIM,
                                             bn_beta + 3 * HIDDIM, NNODES, (unsigned short*)0);

    zero_kernel<<<(NGRAPH * HIDDIM + TB - 1) / TB, TB, 0, stream>>>(out, NGRAPH * HIDDIM);
    pool_part_kernel<<<dim3(NGRAPH, 8), 256, 0, stream>>>(hbuf, gs, ge, out);
    pool_div_kernel<<<NGRAPH, 128, 0, stream>>>(out, gs, ge);
}

// Round 12
// 757.571 us; speedup vs baseline: 1.0980x; 1.0664x over previous
//
#include <hip/hip_runtime.h>
#include <math.h>

#define NNODES 20000
#define NPAD   20096   // 157 * 128
#define NEDGES 160000
#define HIDDIM 128
#define NHEADS 8
#define NGRAPH 64
#define KC 384   // concatenated K (hi | lo | hi)
#define GXTILES 157

typedef short short8 __attribute__((ext_vector_type(8)));
typedef float floatx4 __attribute__((ext_vector_type(4)));
typedef unsigned short ushort4v __attribute__((ext_vector_type(4)));

__device__ inline unsigned short f2bf(float x) {
    unsigned u = __float_as_uint(x);
    u += 0x7fff + ((u >> 16) & 1);
    return (unsigned short)(u >> 16);
}
__device__ inline float bf2f(unsigned short h) {
    return __uint_as_float(((unsigned)h) << 16);
}

// ---------------- utility ----------------
__global__ __launch_bounds__(256) void zero_kernel(float* __restrict__ p, int n) {
    int i = blockIdx.x * blockDim.x + threadIdx.x;
    if (i < n) p[i] = 0.f;
}

// ---------------- CSR build ----------------
__global__ __launch_bounds__(256) void count_deg_kernel(const int* __restrict__ dst,
                                                        int* __restrict__ deg, int e) {
    int i = blockIdx.x * blockDim.x + threadIdx.x;
    if (i < e) atomicAdd(&deg[dst[i]], 1);
}

__global__ __launch_bounds__(256) void scan1_kernel(const int* __restrict__ deg,
                                                    int* __restrict__ chunk,
                                                    int* __restrict__ bsum, int n) {
    __shared__ int buf[256];
    int t = threadIdx.x;
    int i = blockIdx.x * 256 + t;
    int v = (i < n) ? deg[i] : 0;
    buf[t] = v;
    __syncthreads();
    for (int off = 1; off < 256; off <<= 1) {
        int tmp = (t >= off) ? buf[t - off] : 0;
        __syncthreads();
        buf[t] += tmp;
        __syncthreads();
    }
    if (i < n) chunk[i] = buf[t];
    if (t == 255) bsum[blockIdx.x] = buf[255];
}

__global__ __launch_bounds__(128) void scan2_kernel(int* __restrict__ bsum, int nb) {
    __shared__ int buf[128];
    int t = threadIdx.x;
    int v = (t < nb) ? bsum[t] : 0;
    buf[t] = v;
    __syncthreads();
    for (int off = 1; off < 128; off <<= 1) {
        int tmp = (t >= off) ? buf[t - off] : 0;
        __syncthreads();
        buf[t] += tmp;
        __syncthreads();
    }
    if (t < nb) bsum[t] = buf[t] - v;
}

__global__ __launch_bounds__(256) void scan3_kernel(const int* __restrict__ chunk,
                                                    const int* __restrict__ bsum,
                                                    int* __restrict__ offs, int n) {
    int i = blockIdx.x * 256 + threadIdx.x;
    if (i < n) offs[i + 1] = chunk[i] + bsum[i >> 8];
    if (i == 0) offs[0] = 0;
}

__global__ __launch_bounds__(256) void scatter_kernel(const int* __restrict__ src,
                                                      const int* __restrict__ dst,
                                                      const int* __restrict__ offs,
                                                      int* __restrict__ cursor,
                                                      int* __restrict__ csr_src, int e) {
    int i = blockIdx.x * blockDim.x + threadIdx.x;
    if (i < e) {
        int d = dst[i];
        int pos = offs[d] + atomicAdd(&cursor[d], 1);
        csr_src[pos] = src[i];
    }
}

// ---------------- weight prep ----------------
// Row map: [0,1152): layers0-2 qkv (li*384 + {q,k,v}*128 + j)
// [1152,1536): layers0-2 s (li*128 + j) ; [1536,1664): Wp ; [1664,1792): Ws3
// [1792,4864): layer3 qkv (h*384 + {q,k,v}*128 + j)
__global__ __launch_bounds__(128) void prep_w_kernel(
    const float* __restrict__ Wq, const float* __restrict__ Wk,
    const float* __restrict__ Wv, const float* __restrict__ Ws,
    const float* __restrict__ Wp, const float* __restrict__ Ws3,
    const float* __restrict__ Wq3, const float* __restrict__ Wk3,
    const float* __restrict__ Wv3, unsigned short* __restrict__ WtAll) {
    int id = blockIdx.x;
    int k = threadIdx.x;
    float w;
    if (id < 1152) {
        int li = id / 384, n = id % 384, sel = n >> 7, np = n & 127;
        const float* W = (sel == 0) ? Wq : (sel == 1) ? Wk : Wv;
        w = W[li * 16384 + k * 128 + np];
    } else if (id < 1536) {
        int r = id - 1152, li = r >> 7, np = r & 127;
        w = Ws[li * 16384 + k * 128 + np];
    } else if (id < 1664) {
        w = Wp[k * 128 + (id - 1536)];
    } else if (id < 1792) {
        w = Ws3[k * 128 + (id - 1664)];
    } else {
        int r = id - 1792, h = r / 384, j = r % 384, sel = j >> 7, jp = j & 127;
        const float* W = (sel == 0) ? Wq3 : (sel == 1) ? Wk3 : Wv3;
        w = W[k * 1024 + h * 128 + jp];
    }
    unsigned short hi = f2bf(w);
    unsigned short lo = f2bf(w - bf2f(hi));
    unsigned short* dst = WtAll + (size_t)id * KC;
    dst[k] = hi;
    dst[128 + k] = hi;
    dst[256 + k] = lo;
}

// bias map mirrors weights: [0,1152) layer qkv ; [1152,1536) layer s ;
// [1536,4608) layer3 qkv
__global__ __launch_bounds__(256) void prep_bias_kernel(
    const float* __restrict__ bq, const float* __restrict__ bk,
    const float* __restrict__ bv, const float* __restrict__ bs,
    const float* __restrict__ bq3, const float* __restrict__ bk3,
    const float* __restrict__ bv3, float* __restrict__ bcat) {
    int id = blockIdx.x * 256 + threadIdx.x;
    if (id >= 4608) return;
    float v;
    if (id < 1152) {
        int li = id / 384, n = id % 384, sel = n >> 7, np = n & 127;
        const float* b = (sel == 0) ? bq : (sel == 1) ? bk : bv;
        v = b[li * 128 + np];
    } else if (id < 1536) {
        int r = id - 1152, li = r >> 7, np = r & 127;
        v = bs[li * 128 + np];
    } else {
        int r = id - 1536, h = r / 384, j = r % 384, sel = j >> 7, jp = j & 127;
        const float* b = (sel == 0) ? bq3 : (sel == 1) ? bk3 : bv3;
        v = b[h * 128 + jp];
    }
    bcat[id] = v;
}

// ---------------- activation -> split-bf16 A_cat ----------------
__global__ __launch_bounds__(256) void cat_from_kernel(const float* __restrict__ h,
                                                       unsigned short* __restrict__ Acat) {
    int idx = blockIdx.x * 256 + threadIdx.x;
    if (idx >= NPAD * HIDDIM) return;
    int r = idx >> 7, k = idx & 127;
    float x = (r < NNODES) ? h[idx] : 0.f;
    unsigned short hi = f2bf(x);
    unsigned short lo = f2bf(x - bf2f(hi));
    unsigned short* row = Acat + (size_t)r * KC;
    row[k] = hi;
    row[128 + k] = lo;
    row[256 + k] = hi;
}

// ---------------- MFMA GEMM (round-9 core: XCD swizzle, direct stores) ----------------
// 1-D grid of 160*BY blocks; xcd = id&7, bx = (idx/BY)*8+xcd, by = idx%BY: all
// column passes of one 128-node A stripe stay on ONE XCD -> A L2-resident.
// A-operand = Wt rows (features), B-operand = Acat rows (nodes): acc quad = 4
// consecutive features of one node -> vectorized stores.
template <typename OutT, int KG, int BY>
__global__ __launch_bounds__(256) void gemm_mfma_kernel(
    const unsigned short* __restrict__ Acat, const unsigned short* __restrict__ Wt,
    const float* __restrict__ bias, OutT* __restrict__ C, int M, int nrows) {
    int id = blockIdx.x;
    int xcd = id & 7;
    int idx = id >> 3;
    int bx = (idx / BY) * 8 + xcd;
    int by = idx % BY;
    if (bx >= GXTILES) return;
    int lane = threadIdx.x & 63;
    int wave = threadIdx.x >> 6;
    int nodeBase = bx * 128 + (wave & 1) * 64;
    int featBase = by * 128 + (wave >> 1) * 64;
    int m = lane & 15;
    int q = lane >> 4;
    int ko = q * 8;
    const unsigned short* wptr = Wt + (size_t)(featBase + m) * KC + ko;    // A operand
    const unsigned short* aptr = Acat + (size_t)(nodeBase + m) * KC + ko;  // B operand
    floatx4 acc[4][4];  // [feat tile r][node tile c]
#pragma unroll
    for (int r = 0; r < 4; ++r)
#pragma unroll
        for (int c = 0; c < 4; ++c) acc[r][c] = (floatx4){0.f, 0.f, 0.f, 0.f};
#pragma unroll
    for (int kg = 0; kg < KG; ++kg) {
        short8 a[4], b[4];
#pragma unroll
        for (int r = 0; r < 4; ++r) a[r] = *(const short8*)(wptr + (size_t)r * 16 * KC + kg * 32);
#pragma unroll
        for (int c = 0; c < 4; ++c) b[c] = *(const short8*)(aptr + (size_t)c * 16 * KC + kg * 32);
#pragma unroll
        for (int r = 0; r < 4; ++r)
#pragma unroll
            for (int c = 0; c < 4; ++c)
                acc[r][c] = __builtin_amdgcn_mfma_f32_16x16x32_bf16(a[r], b[c], acc[r][c], 0, 0, 0);
    }
#pragma unroll
    for (int r = 0; r < 4; ++r) {
        int f0 = featBase + r * 16 + q * 4;
        float4 bv = *(const float4*)(bias + f0);
#pragma unroll
        for (int c = 0; c < 4; ++c) {
            int node = nodeBase + c * 16 + m;
            if (node < nrows) {
                float v0 = acc[r][c][0] + bv.x;
                float v1 = acc[r][c][1] + bv.y;
                float v2 = acc[r][c][2] + bv.z;
                float v3 = acc[r][c][3] + bv.w;
                if (sizeof(OutT) == 2) {
                    ushort4v o = {f2bf(v0), f2bf(v1), f2bf(v2), f2bf(v3)};
                    *(ushort4v*)((unsigned short*)C + (size_t)node * M + f0) = o;
                } else {
                    float4 o = {v0, v1, v2, v3};
                    *(float4*)((float*)C + (size_t)node * M + f0) = o;
                }
            }
        }
    }
}

// ---------------- attention layers 0-2: qkv bf16 [N][384], s fp32 [N][128] ----------------
__global__ __launch_bounds__(64) void attn_small_kernel(
    const unsigned short* __restrict__ qkv, const float* __restrict__ sfp,
    const float* __restrict__ Wb,
    const int* __restrict__ offs, const int* __restrict__ csr_src,
    float* __restrict__ out) {
    int i = blockIdx.x;
    int l = threadIdx.x;
    int g = l >> 5;
    int d0 = (l & 31) * 4;
    uint2 qraw = *(const uint2*)(qkv + (size_t)i * 384 + d0);
    float q0 = bf2f((unsigned short)(qraw.x & 0xffff)), q1 = bf2f((unsigned short)(qraw.x >> 16));
    float q2 = bf2f((unsigned short)(qraw.y & 0xffff)), q3 = bf2f((unsigned short)(qraw.y >> 16));
    int e0 = offs[i], e1 = offs[i + 1];
    float mm = -1e30f, lac = 0.f;
    float a0 = 0.f, a1 = 0.f, a2 = 0.f, a3 = 0.f;
    for (int e = e0 + g; e < e1; e += 2) {
        int sn = csr_src[e];
        const unsigned short* row = qkv + (size_t)sn * 384;
        uint2 kk = *(const uint2*)(row + 128 + d0);
        uint2 vv = *(const uint2*)(row + 256 + d0);
        float k0 = bf2f((unsigned short)(kk.x & 0xffff)), k1 = bf2f((unsigned short)(kk.x >> 16));
        float k2 = bf2f((unsigned short)(kk.y & 0xffff)), k3 = bf2f((unsigned short)(kk.y >> 16));
        float p = q0 * k0 + q1 * k1 + q2 * k2 + q3 * k3;
        p += __shfl_xor(p, 1);
        p += __shfl_xor(p, 2);
        float logit = p * 0.25f;
        float mnew = fmaxf(mm, logit);
        float sc = __expf(mm - mnew);
        float w = __expf(logit - mnew);
        float v0 = bf2f((unsigned short)(vv.x & 0xffff)), v1 = bf2f((unsigned short)(vv.x >> 16));
        float v2 = bf2f((unsigned short)(vv.y & 0xffff)), v3 = bf2f((unsigned short)(vv.y >> 16));
        a0 = a0 * sc + w * v0;
        a1 = a1 * sc + w * v1;
        a2 = a2 * sc + w * v2;
        a3 = a3 * sc + w * v3;
        lac = lac * sc + w;
        mm = mnew;
    }
    float mo = __shfl_xor(mm, 32), lo = __shfl_xor(lac, 32);
    float b0 = __shfl_xor(a0, 32), b1 = __shfl_xor(a1, 32);
    float b2 = __shfl_xor(a2, 32), b3 = __shfl_xor(a3, 32);
    float ms = fmaxf(mm, mo);
    float s0 = __expf(mm - ms), s1 = __expf(mo - ms);
    a0 = a0 * s0 + b0 * s1;
    a1 = a1 * s0 + b1 * s1;
    a2 = a2 * s0 + b2 * s1;
    a3 = a3 * s0 + b3 * s1;
    lac = lac * s0 + lo * s1;
    float inv = 1.f / (lac + 1e-16f);
    float o0 = a0 * inv, o1 = a1 * inv, o2 = a2 * inv, o3 = a3 * inv;
    float4 rv = *(const float4*)(sfp + (size_t)i * HIDDIM + d0);
    float part = o0 * Wb[d0] + o1 * Wb[d0 + 1] + o2 * Wb[d0 + 2] + o3 * Wb[d0 + 3]
               + rv.x * Wb[128 + d0] + rv.y * Wb[128 + d0 + 1]
               + rv.z * Wb[128 + d0 + 2] + rv.w * Wb[128 + d0 + 3]
               + (o0 - rv.x) * Wb[256 + d0] + (o1 - rv.y) * Wb[256 + d0 + 1]
               + (o2 - rv.z) * Wb[256 + d0 + 2] + (o3 - rv.w) * Wb[256 + d0 + 3];
    if (g) part = 0.f;
#pragma unroll
    for (int msk = 1; msk <= 32; msk <<= 1) part += __shfl_xor(part, msk);
    float gg = 1.f / (1.f + __expf(-part));
    if (g == 0) {
        float4 o4 = {gg * rv.x + (1.f - gg) * o0, gg * rv.y + (1.f - gg) * o1,
                     gg * rv.z + (1.f - gg) * o2, gg * rv.w + (1.f - gg) * o3};
        *(float4*)(out + (size_t)i * HIDDIM + d0) = o4;
    }
}

// ---------------- attention layer 3: merged qkv3 bf16 [N][1536] (4 heads/pass) ----------------
__global__ __launch_bounds__(64) void attn_big_kernel(
    const unsigned short* __restrict__ qkv3,
    const int* __restrict__ offs, const int* __restrict__ csr_src,
    float* __restrict__ oslice) {
    int i = blockIdx.x;
    int y = blockIdx.y;
    int l = threadIdx.x;
    int g = l >> 4;
    int s = l & 15;
    uint4 qq = *(const uint4*)(qkv3 + (size_t)i * 1536 + y * 384 + 8 * s);
    float q0 = bf2f((unsigned short)(qq.x & 0xffff)), q1 = bf2f((unsigned short)(qq.x >> 16));
    float q2 = bf2f((unsigned short)(qq.y & 0xffff)), q3f = bf2f((unsigned short)(qq.y >> 16));
    float q4 = bf2f((unsigned short)(qq.z & 0xffff)), q5 = bf2f((unsigned short)(qq.z >> 16));
    float q6 = bf2f((unsigned short)(qq.w & 0xffff)), q7 = bf2f((unsigned short)(qq.w >> 16));
    int e0 = offs[i], e1 = offs[i + 1];
    float mm = -1e30f, lac = 0.f;
    float ac[8];
#pragma unroll
    for (int j = 0; j < 8; ++j) ac[j] = 0.f;
    for (int e = e0 + g; e < e1; e += 4) {
        int sn = csr_src[e];
        const unsigned short* row = qkv3 + (size_t)sn * 1536 + y * 384 + 8 * s;
        uint4 kk = *(const uint4*)(row + 128);
        uint4 vv = *(const uint4*)(row + 256);
        float k0 = bf2f((unsigned short)(kk.x & 0xffff)), k1 = bf2f((unsigned short)(kk.x >> 16));
        float k2 = bf2f((unsigned short)(kk.y & 0xffff)), k3 = bf2f((unsigned short)(kk.y >> 16));
        float k4 = bf2f((unsigned short)(kk.z & 0xffff)), k5 = bf2f((unsigned short)(kk.z >> 16));
        float k6 = bf2f((unsigned short)(kk.w & 0xffff)), k7 = bf2f((unsigned short)(kk.w >> 16));
        float p = q0 * k0 + q1 * k1 + q2 * k2 + q3f * k3
                + q4 * k4 + q5 * k5 + q6 * k6 + q7 * k7;
        p += __shfl_xor(p, 1);
        p += __shfl_xor(p, 2);
        p += __shfl_xor(p, 4);
        p += __shfl_xor(p, 8);
        float logit = p * 0.08838834764831845f;
        float mnew = fmaxf(mm, logit);
        float sc = __expf(mm - mnew);
        float w = __expf(logit - mnew);
        float v0 = bf2f((unsigned short)(vv.x & 0xffff)), v1 = bf2f((unsigned short)(vv.x >> 16));
        float v2 = bf2f((unsigned short)(vv.y & 0xffff)), v3 = bf2f((unsigned short)(vv.y >> 16));
        float v4 = bf2f((unsigned short)(vv.z & 0xffff)), v5 = bf2f((unsigned short)(vv.z >> 16));
        float v6 = bf2f((unsigned short)(vv.w & 0xffff)), v7 = bf2f((unsigned short)(vv.w >> 16));
        ac[0] = ac[0] * sc + w * v0; ac[1] = ac[1] * sc + w * v1;
        ac[2] = ac[2] * sc + w * v2; ac[3] = ac[3] * sc + w * v3;
        ac[4] = ac[4] * sc + w * v4; ac[5] = ac[5] * sc + w * v5;
        ac[6] = ac[6] * sc + w * v6; ac[7] = ac[7] * sc + w * v7;
        lac = lac * sc + w;
        mm = mnew;
    }
#pragma unroll
    for (int msk = 16; msk <= 32; msk <<= 1) {
        float mo = __shfl_xor(mm, msk), lo = __shfl_xor(lac, msk);
        float bo[8];
#pragma unroll
        for (int j = 0; j < 8; ++j) bo[j] = __shfl_xor(ac[j], msk);
        float ms = fmaxf(mm, mo);
        float s0 = __expf(mm - ms), s1 = __expf(mo - ms);
#pragma unroll
        for (int j = 0; j < 8; ++j) ac[j] = ac[j] * s0 + bo[j] * s1;
        lac = lac * s0 + lo * s1;
        mm = ms;
    }
    if (g == 0) {
        float inv = 1.f / (lac + 1e-16f);
        float4 w0 = {ac[0] * inv, ac[1] * inv, ac[2] * inv, ac[3] * inv};
        float4 w1 = {ac[4] * inv, ac[5] * inv, ac[6] * inv, ac[7] * inv};
        float* o = oslice + ((size_t)y * NNODES + i) * HIDDIM + 8 * s;
        *(float4*)o = w0;
        *(float4*)(o + 4) = w1;
    }
}

// ---------------- beta gate layer 3 (head mean over 8 slices) ----------------
__global__ __launch_bounds__(128) void beta3_kernel(const float* __restrict__ obuf8,
                                                    const float* __restrict__ s,
                                                    const float* __restrict__ Wb,
                                                    float* __restrict__ out) {
    int i = blockIdx.x, t = threadIdx.x;
    float o = 0.f;
#pragma unroll
    for (int y = 0; y < 8; ++y) o += obuf8[((size_t)y * NNODES + i) * HIDDIM + t];
    o *= 0.125f;
    float r = s[(size_t)i * HIDDIM + t];
    float part = o * Wb[t] + r * Wb[128 + t] + (o - r) * Wb[256 + t];
#pragma unroll
    for (int msk = 1; msk <= 32; msk <<= 1) part += __shfl_xor(part, msk);
    __shared__ float wsum[2];
    if ((t & 63) == 0) wsum[t >> 6] = part;
    __syncthreads();
    float tot = wsum[0] + wsum[1];
    float g = 1.f / (1.f + __expf(-tot));
    out[(size_t)i * HIDDIM + t] = g * r + (1.f - g) * o;
}

// ---------------- batchnorm ----------------
__global__ __launch_bounds__(128) void bn_stats_kernel(const float* __restrict__ x,
                                                       float* __restrict__ stat, int n) {
    int t = threadIdx.x;
    float s = 0.f, sq = 0.f;
    for (int i = blockIdx.x; i < n; i += gridDim.x) {
        float v = x[(size_t)i * HIDDIM + t];
        s += v;
        sq += v * v;
    }
    atomicAdd(&stat[t], s);
    atomicAdd(&stat[HIDDIM + t], sq);
}

__global__ __launch_bounds__(128) void bn_apply_kernel(float* __restrict__ x,
                                                       const float* __restrict__ stat,
                                                       const float* __restrict__ gamma,
                                                       const float* __restrict__ beta, int n,
                                                       unsigned short* __restrict__ cat) {
    int t = threadIdx.x;
    float mu = stat[t] / (float)n;
    float var = stat[HIDDIM + t] / (float)n - mu * mu;
    float rs = rsqrtf(var + 1e-5f);
    float g = gamma[t], b = beta[t];
    for (int i = blockIdx.x; i < n; i += gridDim.x) {
        float v = x[(size_t)i * HIDDIM + t];
        v = fmaxf((v - mu) * rs * g + b, 0.f);
        x[(size_t)i * HIDDIM + t] = v;
        if (cat) {
            unsigned short hi = f2bf(v);
            unsigned short lo = f2bf(v - bf2f(hi));
            unsigned short* row = cat + (size_t)i * KC;
            row[t] = hi;
            row[128 + t] = lo;
            row[256 + t] = hi;
        }
    }
}

// ---------------- pool ----------------
__global__ __launch_bounds__(256) void gb_kernel(const int* __restrict__ batch,
                                                 int* __restrict__ gs,
                                                 int* __restrict__ ge, int n) {
    int i = blockIdx.x * 256 + threadIdx.x;
    if (i >= n) return;
    int b = batch[i];
    if (i == 0 || batch[i - 1] != b) gs[b] = i;
    if (i == n - 1 || batch[i + 1] != b) ge[b] = i + 1;
}

__global__ __launch_bounds__(256) void pool_part_kernel(const float* __restrict__ x,
                                                        const int* __restrict__ gs,
                                                        const int* __restrict__ ge,
                                                        float* __restrict__ out) {
    int g = blockIdx.x, c = blockIdx.y;
    int t = threadIdx.x;
    int f = t & 127, half = t >> 7;
    int s = gs[g], e = ge[g];
    float acc = 0.f;
    for (int i = s + 2 * c + half; i < e; i += 16) acc += x[(size_t)i * HIDDIM + f];
    __shared__ float l0[128];
    if (half == 0) l0[f] = acc;
    __syncthreads();
    if (half == 1) atomicAdd(&out[g * HIDDIM + f], l0[f] + acc);
}

__global__ __launch_bounds__(128) void pool_div_kernel(float* __restrict__ out,
                                                       const int* __restrict__ gs,
                                                       const int* __restrict__ ge) {
    int g = blockIdx.x, t = threadIdx.x;
    int c = ge[g] - gs[g];
    out[g * HIDDIM + t] /= (float)(c > 0 ? c : 1);
}

// ---------------- host ----------------
extern "C" void kernel_launch(void* const* d_in, const int* in_sizes, int n_in,
                              void* d_out, int out_size, void* d_ws, size_t ws_size,
                              hipStream_t stream) {
    const float* x       = (const float*)d_in[0];
    const int*   ei      = (const int*)d_in[1];
    const int*   batch   = (const int*)d_in[2];
    const float* Wp      = (const float*)d_in[3];
    const float* bp      = (const float*)d_in[4];
    const float* Wq      = (const float*)d_in[5];
    const float* bq      = (const float*)d_in[6];
    const float* Wk      = (const float*)d_in[7];
    const float* bk      = (const float*)d_in[8];
    const float* Wv      = (const float*)d_in[9];
    const float* bv      = (const float*)d_in[10];
    const float* Ws      = (const float*)d_in[11];
    const float* bs      = (const float*)d_in[12];
    const float* Wbeta   = (const float*)d_in[13];
    const float* Wq3     = (const float*)d_in[14];
    const float* bq3     = (const float*)d_in[15];
    const float* Wk3     = (const float*)d_in[16];
    const float* bk3     = (const float*)d_in[17];
    const float* Wv3     = (const float*)d_in[18];
    const float* bv3     = (const float*)d_in[19];
    const float* Ws3     = (const float*)d_in[20];
    const float* bs3     = (const float*)d_in[21];
    const float* Wbeta3  = (const float*)d_in[22];
    const float* bn_gamma = (const float*)d_in[23];
    const float* bn_beta  = (const float*)d_in[24];
    float* out = (float*)d_out;

    const int* esrc = ei;
    const int* edst = ei + NEDGES;

    char* wpc = (char*)d_ws;
    auto alloc = [&](size_t nbytes) -> char* {
        char* p = wpc;
        wpc += (nbytes + 255) & ~(size_t)255;
        return p;
    };
    unsigned short* Acat  = (unsigned short*)alloc((size_t)NPAD * KC * 2);      // 15.4 MB
    unsigned short* WtAll = (unsigned short*)alloc((size_t)4864 * KC * 2);      // 3.7 MB
    float* bcat   = (float*)alloc(4608 * 4);
    unsigned short* qkvb = (unsigned short*)alloc((size_t)NNODES * 1536 * 2);   // 61.4 MB
    float* sfp    = (float*)alloc((size_t)NNODES * HIDDIM * 4);                 // 10.2 MB
    float* obuf8  = (float*)alloc((size_t)8 * NNODES * HIDDIM * 4);             // 81.9 MB
    float* hbuf   = (float*)alloc((size_t)NNODES * HIDDIM * 4);
    float* obuf   = (float*)alloc((size_t)NNODES * HIDDIM * 4);
    float* sb     = (float*)alloc((size_t)NNODES * HIDDIM * 4);
    int*   deg    = (int*)alloc((2 * NNODES + 128 + 4 * 256) * 4);
    int*   cursor = deg + NNODES;
    int*   gs     = deg + 2 * NNODES;
    int*   ge     = gs + NGRAPH;
    float* bnstat4 = (float*)(deg + 2 * NNODES + 128);
    int*   chunk  = (int*)alloc(NNODES * 4);
    int*   bsum   = (int*)alloc(128 * 4);
    int*   offs   = (int*)alloc((NNODES + 1) * 4);
    int*   csrsrc = (int*)alloc(NEDGES * 4);

    unsigned short* WtQKV = WtAll;                       // [3][384][KC]
    unsigned short* WtS   = WtAll + (size_t)1152 * KC;   // [3][128][KC]
    unsigned short* Wpt   = WtAll + (size_t)1536 * KC;
    unsigned short* Ws3t  = WtAll + (size_t)1664 * KC;
    unsigned short* Wt3   = WtAll + (size_t)1792 * KC;   // [8][384][KC]
    float* bQKV = bcat;          // [3][384]
    float* bS   = bcat + 1152;   // [3][128]
    float* b3   = bcat + 1536;   // [8][384]

    const int TB = 256;
    const int ZWORDS = 2 * NNODES + 128 + 4 * 256;
    zero_kernel<<<(ZWORDS + TB - 1) / TB, TB, 0, stream>>>((float*)deg, ZWORDS);
    count_deg_kernel<<<(NEDGES + TB - 1) / TB, TB, 0, stream>>>(edst, deg, NEDGES);
    const int NB = (NNODES + 255) / 256;
    scan1_kernel<<<NB, 256, 0, stream>>>(deg, chunk, bsum, NNODES);
    scan2_kernel<<<1, 128, 0, stream>>>(bsum, NB);
    scan3_kernel<<<NB, 256, 0, stream>>>(chunk, bsum, offs, NNODES);
    scatter_kernel<<<(NEDGES + TB - 1) / TB, TB, 0, stream>>>(esrc, edst, offs, cursor, csrsrc, NEDGES);
    gb_kernel<<<(NNODES + TB - 1) / TB, TB, 0, stream>>>(batch, gs, ge, NNODES);

    prep_w_kernel<<<4864, 128, 0, stream>>>(Wq, Wk, Wv, Ws, Wp, Ws3, Wq3, Wk3, Wv3, WtAll);
    prep_bias_kernel<<<(4608 + TB - 1) / TB, TB, 0, stream>>>(bq, bk, bv, bs, bq3, bk3, bv3, bcat);

    const int CATB = (NPAD * HIDDIM + TB - 1) / TB;
    const int GSW = 8 * ((GXTILES + 7) / 8);  // 160 swizzled x-slots

    cat_from_kernel<<<CATB, TB, 0, stream>>>(x, Acat);
    gemm_mfma_kernel<float, 12, 1><<<GSW * 1, 256, 0, stream>>>(Acat, Wpt, bp, hbuf, 128, NNODES);
    cat_from_kernel<<<CATB, TB, 0, stream>>>(hbuf, Acat);

    for (int li = 0; li < 3; ++li) {
        gemm_mfma_kernel<unsigned short, 8, 3><<<GSW * 3, 256, 0, stream>>>(
            Acat, WtQKV + (size_t)li * 384 * KC, bQKV + li * 384, qkvb, 384, NNODES);
        gemm_mfma_kernel<float, 12, 1><<<GSW * 1, 256, 0, stream>>>(
            Acat, WtS + (size_t)li * 128 * KC, bS + li * 128, sfp, 128, NNODES);
        attn_small_kernel<<<NNODES, 64, 0, stream>>>(qkvb, sfp, Wbeta + li * 384,
                                                     offs, csrsrc, obuf);
        float* st = bnstat4 + li * 256;
        bn_stats_kernel<<<640, 128, 0, stream>>>(obuf, st, NNODES);
        bn_apply_kernel<<<512, 128, 0, stream>>>(obuf, st, bn_gamma + li * HIDDIM,
                                                 bn_beta + li * HIDDIM, NNODES, Acat);
    }

    // ---- layer 3: two passes of 4 heads, merged q|k|v GEMM ----
    for (int h2 = 0; h2 < 2; ++h2) {
        gemm_mfma_kernel<unsigned short, 8, 12><<<GSW * 12, 256, 0, stream>>>(
            Acat, Wt3 + (size_t)h2 * 1536 * KC, b3 + h2 * 1536, qkvb, 1536, NNODES);
        attn_big_kernel<<<dim3(NNODES, 4), 64, 0, stream>>>(
            qkvb, offs, csrsrc, obuf8 + (size_t)h2 * 4 * NNODES * HIDDIM);
    }
    gemm_mfma_kernel<float, 12, 1><<<GSW * 1, 256, 0, stream>>>(Acat, Ws3t, bs3, sb, 128, NNODES);
    beta3_kernel<<<NNODES, 128, 0, stream>>>(obuf8, sb, Wbeta3, hbuf);
    float* st3 = bnstat4 + 3 * 256;
    bn_stats_kernel<<<640, 128, 0, stream>>>(hbuf, st3, NNODES);
    bn_apply_kernel<<<512, 128, 0, stream>>>(hbuf, st3, bn_gamma + 3 * HIDDIM,
                                             bn_beta + 3 * HIDDIM, NNODES, (unsigned short*)0);

    zero_kernel<<<(NGRAPH * HIDDIM + TB - 1) / TB, TB, 0, stream>>>(out, NGRAPH * HIDDIM);
    pool_part_kernel<<<dim3(NGRAPH, 8), 256, 0, stream>>>(hbuf, gs, ge, out);
    pool_div_kernel<<<NGRAPH, 128, 0, stream>>>(out, gs, ge);
}

// Round 13
// 727.252 us; speedup vs baseline: 1.1438x; 1.0417x over previous
//
#include <hip/hip_runtime.h>
#include <math.h>

#define NNODES 20000
#define NPAD   20096   // 157 * 128
#define NEDGES 160000
#define HIDDIM 128
#define NHEADS 8
#define NGRAPH 64
#define KC 384   // concatenated K (hi | lo | hi)
#define GXTILES 157

typedef short short8 __attribute__((ext_vector_type(8)));
typedef float floatx4 __attribute__((ext_vector_type(4)));
typedef unsigned short ushort4v __attribute__((ext_vector_type(4)));

__device__ inline unsigned short f2bf(float x) {
    unsigned u = __float_as_uint(x);
    u += 0x7fff + ((u >> 16) & 1);
    return (unsigned short)(u >> 16);
}
__device__ inline float bf2f(unsigned short h) {
    return __uint_as_float(((unsigned)h) << 16);
}

// ---------------- utility ----------------
__global__ __launch_bounds__(256) void zero_kernel(float* __restrict__ p, int n) {
    int i = blockIdx.x * blockDim.x + threadIdx.x;
    if (i < n) p[i] = 0.f;
}

// ---------------- CSR build ----------------
__global__ __launch_bounds__(256) void count_deg_kernel(const int* __restrict__ dst,
                                                        int* __restrict__ deg, int e) {
    int i = blockIdx.x * blockDim.x + threadIdx.x;
    if (i < e) atomicAdd(&deg[dst[i]], 1);
}

__global__ __launch_bounds__(256) void scan1_kernel(const int* __restrict__ deg,
                                                    int* __restrict__ chunk,
                                                    int* __restrict__ bsum, int n) {
    __shared__ int buf[256];
    int t = threadIdx.x;
    int i = blockIdx.x * 256 + t;
    int v = (i < n) ? deg[i] : 0;
    buf[t] = v;
    __syncthreads();
    for (int off = 1; off < 256; off <<= 1) {
        int tmp = (t >= off) ? buf[t - off] : 0;
        __syncthreads();
        buf[t] += tmp;
        __syncthreads();
    }
    if (i < n) chunk[i] = buf[t];
    if (t == 255) bsum[blockIdx.x] = buf[255];
}

__global__ __launch_bounds__(128) void scan2_kernel(int* __restrict__ bsum, int nb) {
    __shared__ int buf[128];
    int t = threadIdx.x;
    int v = (t < nb) ? bsum[t] : 0;
    buf[t] = v;
    __syncthreads();
    for (int off = 1; off < 128; off <<= 1) {
        int tmp = (t >= off) ? buf[t - off] : 0;
        __syncthreads();
        buf[t] += tmp;
        __syncthreads();
    }
    if (t < nb) bsum[t] = buf[t] - v;
}

__global__ __launch_bounds__(256) void scan3_kernel(const int* __restrict__ chunk,
                                                    const int* __restrict__ bsum,
                                                    int* __restrict__ offs, int n) {
    int i = blockIdx.x * 256 + threadIdx.x;
    if (i < n) offs[i + 1] = chunk[i] + bsum[i >> 8];
    if (i == 0) offs[0] = 0;
}

__global__ __launch_bounds__(256) void scatter_kernel(const int* __restrict__ src,
                                                      const int* __restrict__ dst,
                                                      const int* __restrict__ offs,
                                                      int* __restrict__ cursor,
                                                      int* __restrict__ csr_src, int e) {
    int i = blockIdx.x * blockDim.x + threadIdx.x;
    if (i < e) {
        int d = dst[i];
        int pos = offs[d] + atomicAdd(&cursor[d], 1);
        csr_src[pos] = src[i];
    }
}

// ---------------- weight prep ----------------
// Row map: [0,1152): layers0-2 qkv (li*384 + {q,k,v}*128 + j)
// [1152,1536): layers0-2 s (li*128 + j) ; [1536,1664): Wp ; [1664,1792): Ws3
// [1792,4864): layer3 qkv (h*384 + {q,k,v}*128 + j)
__global__ __launch_bounds__(128) void prep_w_kernel(
    const float* __restrict__ Wq, const float* __restrict__ Wk,
    const float* __restrict__ Wv, const float* __restrict__ Ws,
    const float* __restrict__ Wp, const float* __restrict__ Ws3,
    const float* __restrict__ Wq3, const float* __restrict__ Wk3,
    const float* __restrict__ Wv3, unsigned short* __restrict__ WtAll) {
    int id = blockIdx.x;
    int k = threadIdx.x;
    float w;
    if (id < 1152) {
        int li = id / 384, n = id % 384, sel = n >> 7, np = n & 127;
        const float* W = (sel == 0) ? Wq : (sel == 1) ? Wk : Wv;
        w = W[li * 16384 + k * 128 + np];
    } else if (id < 1536) {
        int r = id - 1152, li = r >> 7, np = r & 127;
        w = Ws[li * 16384 + k * 128 + np];
    } else if (id < 1664) {
        w = Wp[k * 128 + (id - 1536)];
    } else if (id < 1792) {
        w = Ws3[k * 128 + (id - 1664)];
    } else {
        int r = id - 1792, h = r / 384, j = r % 384, sel = j >> 7, jp = j & 127;
        const float* W = (sel == 0) ? Wq3 : (sel == 1) ? Wk3 : Wv3;
        w = W[k * 1024 + h * 128 + jp];
    }
    unsigned short hi = f2bf(w);
    unsigned short lo = f2bf(w - bf2f(hi));
    unsigned short* dst = WtAll + (size_t)id * KC;
    dst[k] = hi;
    dst[128 + k] = hi;
    dst[256 + k] = lo;
}

__global__ __launch_bounds__(256) void prep_bias_kernel(
    const float* __restrict__ bq, const float* __restrict__ bk,
    const float* __restrict__ bv, const float* __restrict__ bs,
    const float* __restrict__ bq3, const float* __restrict__ bk3,
    const float* __restrict__ bv3, float* __restrict__ bcat) {
    int id = blockIdx.x * 256 + threadIdx.x;
    if (id >= 4608) return;
    float v;
    if (id < 1152) {
        int li = id / 384, n = id % 384, sel = n >> 7, np = n & 127;
        const float* b = (sel == 0) ? bq : (sel == 1) ? bk : bv;
        v = b[li * 128 + np];
    } else if (id < 1536) {
        int r = id - 1152, li = r >> 7, np = r & 127;
        v = bs[li * 128 + np];
    } else {
        int r = id - 1536, h = r / 384, j = r % 384, sel = j >> 7, jp = j & 127;
        const float* b = (sel == 0) ? bq3 : (sel == 1) ? bk3 : bv3;
        v = b[h * 128 + jp];
    }
    bcat[id] = v;
}

// ---------------- activation -> split-bf16 A_cat ----------------
__global__ __launch_bounds__(256) void cat_from_kernel(const float* __restrict__ h,
                                                       unsigned short* __restrict__ Acat) {
    int idx = blockIdx.x * 256 + threadIdx.x;
    if (idx >= NPAD * HIDDIM) return;
    int r = idx >> 7, k = idx & 127;
    float x = (r < NNODES) ? h[idx] : 0.f;
    unsigned short hi = f2bf(x);
    unsigned short lo = f2bf(x - bf2f(hi));
    unsigned short* row = Acat + (size_t)r * KC;
    row[k] = hi;
    row[128 + k] = lo;
    row[256 + k] = hi;
}

// ---------------- MFMA GEMM (XCD swizzle, direct stores, line-grouped epilogue) ----------------
// 1-D grid of 160*BY blocks; xcd = id&7, bx = (idx/BY)*8+xcd, by = idx%BY: all
// column passes of one 128-node A stripe stay on ONE XCD -> A L2-resident.
// A-operand = Wt rows (features), B-operand = Acat rows (nodes): acc quad = 4
// consecutive features of one node. Epilogue: c-outer/r-inner so the 4 stores
// completing one node's 128B line are consecutive instructions (write-combine).
template <typename OutT, int KG, int BY>
__global__ __launch_bounds__(256) void gemm_mfma_kernel(
    const unsigned short* __restrict__ Acat, const unsigned short* __restrict__ Wt,
    const float* __restrict__ bias, OutT* __restrict__ C, int M, int nrows) {
    int id = blockIdx.x;
    int xcd = id & 7;
    int idx = id >> 3;
    int bx = (idx / BY) * 8 + xcd;
    int by = idx % BY;
    if (bx >= GXTILES) return;
    int lane = threadIdx.x & 63;
    int wave = threadIdx.x >> 6;
    int nodeBase = bx * 128 + (wave & 1) * 64;
    int featBase = by * 128 + (wave >> 1) * 64;
    int m = lane & 15;
    int q = lane >> 4;
    int ko = q * 8;
    const unsigned short* wptr = Wt + (size_t)(featBase + m) * KC + ko;    // A operand
    const unsigned short* aptr = Acat + (size_t)(nodeBase + m) * KC + ko;  // B operand
    floatx4 acc[4][4];  // [feat tile r][node tile c]
#pragma unroll
    for (int r = 0; r < 4; ++r)
#pragma unroll
        for (int c = 0; c < 4; ++c) acc[r][c] = (floatx4){0.f, 0.f, 0.f, 0.f};
#pragma unroll
    for (int kg = 0; kg < KG; ++kg) {
        short8 a[4], b[4];
#pragma unroll
        for (int r = 0; r < 4; ++r) a[r] = *(const short8*)(wptr + (size_t)r * 16 * KC + kg * 32);
#pragma unroll
        for (int c = 0; c < 4; ++c) b[c] = *(const short8*)(aptr + (size_t)c * 16 * KC + kg * 32);
#pragma unroll
        for (int r = 0; r < 4; ++r)
#pragma unroll
            for (int c = 0; c < 4; ++c)
                acc[r][c] = __builtin_amdgcn_mfma_f32_16x16x32_bf16(a[r], b[c], acc[r][c], 0, 0, 0);
    }
    float4 bv[4];
#pragma unroll
    for (int r = 0; r < 4; ++r) bv[r] = *(const float4*)(bias + featBase + r * 16 + q * 4);
#pragma unroll
    for (int c = 0; c < 4; ++c) {
        int node = nodeBase + c * 16 + m;
        if (node < nrows) {
#pragma unroll
            for (int r = 0; r < 4; ++r) {
                int f0 = featBase + r * 16 + q * 4;
                float v0 = acc[r][c][0] + bv[r].x;
                float v1 = acc[r][c][1] + bv[r].y;
                float v2 = acc[r][c][2] + bv[r].z;
                float v3 = acc[r][c][3] + bv[r].w;
                if (sizeof(OutT) == 2) {
                    ushort4v o = {f2bf(v0), f2bf(v1), f2bf(v2), f2bf(v3)};
                    *(ushort4v*)((unsigned short*)C + (size_t)node * M + f0) = o;
                } else {
                    float4 o = {v0, v1, v2, v3};
                    *(float4*)((float*)C + (size_t)node * M + f0) = o;
                }
            }
        }
    }
}

// ---------------- attention layers 0-2: qkv bf16 [N][384], s fp32 [N][128] ----------------
__global__ __launch_bounds__(64) void attn_small_kernel(
    const unsigned short* __restrict__ qkv, const float* __restrict__ sfp,
    const float* __restrict__ Wb,
    const int* __restrict__ offs, const int* __restrict__ csr_src,
    float* __restrict__ out) {
    int i = blockIdx.x;
    int l = threadIdx.x;
    int g = l >> 5;
    int d0 = (l & 31) * 4;
    uint2 qraw = *(const uint2*)(qkv + (size_t)i * 384 + d0);
    float q0 = bf2f((unsigned short)(qraw.x & 0xffff)), q1 = bf2f((unsigned short)(qraw.x >> 16));
    float q2 = bf2f((unsigned short)(qraw.y & 0xffff)), q3 = bf2f((unsigned short)(qraw.y >> 16));
    int e0 = offs[i], e1 = offs[i + 1];
    float mm = -1e30f, lac = 0.f;
    float a0 = 0.f, a1 = 0.f, a2 = 0.f, a3 = 0.f;
    for (int e = e0 + g; e < e1; e += 2) {
        int sn = csr_src[e];
        const unsigned short* row = qkv + (size_t)sn * 384;
        uint2 kk = *(const uint2*)(row + 128 + d0);
        uint2 vv = *(const uint2*)(row + 256 + d0);
        float k0 = bf2f((unsigned short)(kk.x & 0xffff)), k1 = bf2f((unsigned short)(kk.x >> 16));
        float k2 = bf2f((unsigned short)(kk.y & 0xffff)), k3 = bf2f((unsigned short)(kk.y >> 16));
        float p = q0 * k0 + q1 * k1 + q2 * k2 + q3 * k3;
        p += __shfl_xor(p, 1);
        p += __shfl_xor(p, 2);
        float logit = p * 0.25f;
        float mnew = fmaxf(mm, logit);
        float sc = __expf(mm - mnew);
        float w = __expf(logit - mnew);
        float v0 = bf2f((unsigned short)(vv.x & 0xffff)), v1 = bf2f((unsigned short)(vv.x >> 16));
        float v2 = bf2f((unsigned short)(vv.y & 0xffff)), v3 = bf2f((unsigned short)(vv.y >> 16));
        a0 = a0 * sc + w * v0;
        a1 = a1 * sc + w * v1;
        a2 = a2 * sc + w * v2;
        a3 = a3 * sc + w * v3;
        lac = lac * sc + w;
        mm = mnew;
    }
    float mo = __shfl_xor(mm, 32), lo = __shfl_xor(lac, 32);
    float b0 = __shfl_xor(a0, 32), b1 = __shfl_xor(a1, 32);
    float b2 = __shfl_xor(a2, 32), b3 = __shfl_xor(a3, 32);
    float ms = fmaxf(mm, mo);
    float s0 = __expf(mm - ms), s1 = __expf(mo - ms);
    a0 = a0 * s0 + b0 * s1;
    a1 = a1 * s0 + b1 * s1;
    a2 = a2 * s0 + b2 * s1;
    a3 = a3 * s0 + b3 * s1;
    lac = lac * s0 + lo * s1;
    float inv = 1.f / (lac + 1e-16f);
    float o0 = a0 * inv, o1 = a1 * inv, o2 = a2 * inv, o3 = a3 * inv;
    float4 rv = *(const float4*)(sfp + (size_t)i * HIDDIM + d0);
    float part = o0 * Wb[d0] + o1 * Wb[d0 + 1] + o2 * Wb[d0 + 2] + o3 * Wb[d0 + 3]
               + rv.x * Wb[128 + d0] + rv.y * Wb[128 + d0 + 1]
               + rv.z * Wb[128 + d0 + 2] + rv.w * Wb[128 + d0 + 3]
               + (o0 - rv.x) * Wb[256 + d0] + (o1 - rv.y) * Wb[256 + d0 + 1]
               + (o2 - rv.z) * Wb[256 + d0 + 2] + (o3 - rv.w) * Wb[256 + d0 + 3];
    if (g) part = 0.f;
#pragma unroll
    for (int msk = 1; msk <= 32; msk <<= 1) part += __shfl_xor(part, msk);
    float gg = 1.f / (1.f + __expf(-part));
    if (g == 0) {
        float4 o4 = {gg * rv.x + (1.f - gg) * o0, gg * rv.y + (1.f - gg) * o1,
                     gg * rv.z + (1.f - gg) * o2, gg * rv.w + (1.f - gg) * o3};
        *(float4*)(out + (size_t)i * HIDDIM + d0) = o4;
    }
}

// ---------------- attention layer 3: merged qkv3 bf16 [N][3072] (8 heads) ----------------
// writes obuf8 in bf16: [8][N][128]
__global__ __launch_bounds__(64) void attn_big_kernel(
    const unsigned short* __restrict__ qkv3,
    const int* __restrict__ offs, const int* __restrict__ csr_src,
    unsigned short* __restrict__ obuf8) {
    int i = blockIdx.x;
    int y = blockIdx.y;   // head 0..7
    int l = threadIdx.x;
    int g = l >> 4;
    int s = l & 15;
    uint4 qq = *(const uint4*)(qkv3 + (size_t)i * 3072 + y * 384 + 8 * s);
    float q0 = bf2f((unsigned short)(qq.x & 0xffff)), q1 = bf2f((unsigned short)(qq.x >> 16));
    float q2 = bf2f((unsigned short)(qq.y & 0xffff)), q3f = bf2f((unsigned short)(qq.y >> 16));
    float q4 = bf2f((unsigned short)(qq.z & 0xffff)), q5 = bf2f((unsigned short)(qq.z >> 16));
    float q6 = bf2f((unsigned short)(qq.w & 0xffff)), q7 = bf2f((unsigned short)(qq.w >> 16));
    int e0 = offs[i], e1 = offs[i + 1];
    float mm = -1e30f, lac = 0.f;
    float ac[8];
#pragma unroll
    for (int j = 0; j < 8; ++j) ac[j] = 0.f;
    for (int e = e0 + g; e < e1; e += 4) {
        int sn = csr_src[e];
        const unsigned short* row = qkv3 + (size_t)sn * 3072 + y * 384 + 8 * s;
        uint4 kk = *(const uint4*)(row + 128);
        uint4 vv = *(const uint4*)(row + 256);
        float k0 = bf2f((unsigned short)(kk.x & 0xffff)), k1 = bf2f((unsigned short)(kk.x >> 16));
        float k2 = bf2f((unsigned short)(kk.y & 0xffff)), k3 = bf2f((unsigned short)(kk.y >> 16));
        float k4 = bf2f((unsigned short)(kk.z & 0xffff)), k5 = bf2f((unsigned short)(kk.z >> 16));
        float k6 = bf2f((unsigned short)(kk.w & 0xffff)), k7 = bf2f((unsigned short)(kk.w >> 16));
        float p = q0 * k0 + q1 * k1 + q2 * k2 + q3f * k3
                + q4 * k4 + q5 * k5 + q6 * k6 + q7 * k7;
        p += __shfl_xor(p, 1);
        p += __shfl_xor(p, 2);
        p += __shfl_xor(p, 4);
        p += __shfl_xor(p, 8);
        float logit = p * 0.08838834764831845f;
        float mnew = fmaxf(mm, logit);
        float sc = __expf(mm - mnew);
        float w = __expf(logit - mnew);
        float v0 = bf2f((unsigned short)(vv.x & 0xffff)), v1 = bf2f((unsigned short)(vv.x >> 16));
        float v2 = bf2f((unsigned short)(vv.y & 0xffff)), v3 = bf2f((unsigned short)(vv.y >> 16));
        float v4 = bf2f((unsigned short)(vv.z & 0xffff)), v5 = bf2f((unsigned short)(vv.z >> 16));
        float v6 = bf2f((unsigned short)(vv.w & 0xffff)), v7 = bf2f((unsigned short)(vv.w >> 16));
        ac[0] = ac[0] * sc + w * v0; ac[1] = ac[1] * sc + w * v1;
        ac[2] = ac[2] * sc + w * v2; ac[3] = ac[3] * sc + w * v3;
        ac[4] = ac[4] * sc + w * v4; ac[5] = ac[5] * sc + w * v5;
        ac[6] = ac[6] * sc + w * v6; ac[7] = ac[7] * sc + w * v7;
        lac = lac * sc + w;
        mm = mnew;
    }
#pragma unroll
    for (int msk = 16; msk <= 32; msk <<= 1) {
        float mo = __shfl_xor(mm, msk), lo = __shfl_xor(lac, msk);
        float bo[8];
#pragma unroll
        for (int j = 0; j < 8; ++j) bo[j] = __shfl_xor(ac[j], msk);
        float ms = fmaxf(mm, mo);
        float s0 = __expf(mm - ms), s1 = __expf(mo - ms);
#pragma unroll
        for (int j = 0; j < 8; ++j) ac[j] = ac[j] * s0 + bo[j] * s1;
        lac = lac * s0 + lo * s1;
        mm = ms;
    }
    if (g == 0) {
        float inv = 1.f / (lac + 1e-16f);
        ushort4v w0 = {f2bf(ac[0] * inv), f2bf(ac[1] * inv), f2bf(ac[2] * inv), f2bf(ac[3] * inv)};
        ushort4v w1 = {f2bf(ac[4] * inv), f2bf(ac[5] * inv), f2bf(ac[6] * inv), f2bf(ac[7] * inv)};
        unsigned short* o = obuf8 + ((size_t)y * NNODES + i) * HIDDIM + 8 * s;
        *(ushort4v*)o = w0;
        *(ushort4v*)(o + 4) = w1;
    }
}

// ---------------- beta gate layer 3 (head mean over 8 bf16 slices) ----------------
__global__ __launch_bounds__(128) void beta3_kernel(const unsigned short* __restrict__ obuf8,
                                                    const float* __restrict__ s,
                                                    const float* __restrict__ Wb,
                                                    float* __restrict__ out) {
    int i = blockIdx.x, t = threadIdx.x;
    float o = 0.f;
#pragma unroll
    for (int y = 0; y < 8; ++y) o += bf2f(obuf8[((size_t)y * NNODES + i) * HIDDIM + t]);
    o *= 0.125f;
    float r = s[(size_t)i * HIDDIM + t];
    float part = o * Wb[t] + r * Wb[128 + t] + (o - r) * Wb[256 + t];
#pragma unroll
    for (int msk = 1; msk <= 32; msk <<= 1) part += __shfl_xor(part, msk);
    __shared__ float wsum[2];
    if ((t & 63) == 0) wsum[t >> 6] = part;
    __syncthreads();
    float tot = wsum[0] + wsum[1];
    float g = 1.f / (1.f + __expf(-tot));
    out[(size_t)i * HIDDIM + t] = g * r + (1.f - g) * o;
}

// ---------------- batchnorm ----------------
__global__ __launch_bounds__(128) void bn_stats_kernel(const float* __restrict__ x,
                                                       float* __restrict__ stat, int n) {
    int t = threadIdx.x;
    float s = 0.f, sq = 0.f;
    for (int i = blockIdx.x; i < n; i += gridDim.x) {
        float v = x[(size_t)i * HIDDIM + t];
        s += v;
        sq += v * v;
    }
    atomicAdd(&stat[t], s);
    atomicAdd(&stat[HIDDIM + t], sq);
}

__global__ __launch_bounds__(128) void bn_apply_kernel(float* __restrict__ x,
                                                       const float* __restrict__ stat,
                                                       const float* __restrict__ gamma,
                                                       const float* __restrict__ beta, int n,
                                                       unsigned short* __restrict__ cat) {
    int t = threadIdx.x;
    float mu = stat[t] / (float)n;
    float var = stat[HIDDIM + t] / (float)n - mu * mu;
    float rs = rsqrtf(var + 1e-5f);
    float g = gamma[t], b = beta[t];
    for (int i = blockIdx.x; i < n; i += gridDim.x) {
        float v = x[(size_t)i * HIDDIM + t];
        v = fmaxf((v - mu) * rs * g + b, 0.f);
        x[(size_t)i * HIDDIM + t] = v;
        if (cat) {
            unsigned short hi = f2bf(v);
            unsigned short lo = f2bf(v - bf2f(hi));
            unsigned short* row = cat + (size_t)i * KC;
            row[t] = hi;
            row[128 + t] = lo;
            row[256 + t] = hi;
        }
    }
}

// ---------------- pool ----------------
__global__ __launch_bounds__(256) void gb_kernel(const int* __restrict__ batch,
                                                 int* __restrict__ gs,
                                                 int* __restrict__ ge, int n) {
    int i = blockIdx.x * 256 + threadIdx.x;
    if (i >= n) return;
    int b = batch[i];
    if (i == 0 || batch[i - 1] != b) gs[b] = i;
    if (i == n - 1 || batch[i + 1] != b) ge[b] = i + 1;
}

__global__ __launch_bounds__(256) void pool_part_kernel(const float* __restrict__ x,
                                                        const int* __restrict__ gs,
                                                        const int* __restrict__ ge,
                                                        float* __restrict__ out) {
    int g = blockIdx.x, c = blockIdx.y;
    int t = threadIdx.x;
    int f = t & 127, half = t >> 7;
    int s = gs[g], e = ge[g];
    float acc = 0.f;
    for (int i = s + 2 * c + half; i < e; i += 16) acc += x[(size_t)i * HIDDIM + f];
    __shared__ float l0[128];
    if (half == 0) l0[f] = acc;
    __syncthreads();
    if (half == 1) atomicAdd(&out[g * HIDDIM + f], l0[f] + acc);
}

__global__ __launch_bounds__(128) void pool_div_kernel(float* __restrict__ out,
                                                       const int* __restrict__ gs,
                                                       const int* __restrict__ ge) {
    int g = blockIdx.x, t = threadIdx.x;
    int c = ge[g] - gs[g];
    out[g * HIDDIM + t] /= (float)(c > 0 ? c : 1);
}

// ---------------- host ----------------
extern "C" void kernel_launch(void* const* d_in, const int* in_sizes, int n_in,
                              void* d_out, int out_size, void* d_ws, size_t ws_size,
                              hipStream_t stream) {
    const float* x       = (const float*)d_in[0];
    const int*   ei      = (const int*)d_in[1];
    const int*   batch   = (const int*)d_in[2];
    const float* Wp      = (const float*)d_in[3];
    const float* bp      = (const float*)d_in[4];
    const float* Wq      = (const float*)d_in[5];
    const float* bq      = (const float*)d_in[6];
    const float* Wk      = (const float*)d_in[7];
    const float* bk      = (const float*)d_in[8];
    const float* Wv      = (const float*)d_in[9];
    const float* bv      = (const float*)d_in[10];
    const float* Ws      = (const float*)d_in[11];
    const float* bs      = (const float*)d_in[12];
    const float* Wbeta   = (const float*)d_in[13];
    const float* Wq3     = (const float*)d_in[14];
    const float* bq3     = (const float*)d_in[15];
    const float* Wk3     = (const float*)d_in[16];
    const float* bk3     = (const float*)d_in[17];
    const float* Wv3     = (const float*)d_in[18];
    const float* bv3     = (const float*)d_in[19];
    const float* Ws3     = (const float*)d_in[20];
    const float* bs3     = (const float*)d_in[21];
    const float* Wbeta3  = (const float*)d_in[22];
    const float* bn_gamma = (const float*)d_in[23];
    const float* bn_beta  = (const float*)d_in[24];
    float* out = (float*)d_out;

    const int* esrc = ei;
    const int* edst = ei + NEDGES;

    char* wpc = (char*)d_ws;
    auto alloc = [&](size_t nbytes) -> char* {
        char* p = wpc;
        wpc += (nbytes + 255) & ~(size_t)255;
        return p;
    };
    unsigned short* Acat  = (unsigned short*)alloc((size_t)NPAD * KC * 2);      // 15.4 MB
    unsigned short* WtAll = (unsigned short*)alloc((size_t)4864 * KC * 2);      // 3.7 MB
    float* bcat   = (float*)alloc(4608 * 4);
    unsigned short* qkv3b = (unsigned short*)alloc((size_t)NNODES * 3072 * 2);  // 122.9 MB
    float* sfp    = (float*)alloc((size_t)NNODES * HIDDIM * 4);                 // 10.2 MB
    unsigned short* obuf8 = (unsigned short*)alloc((size_t)8 * NNODES * HIDDIM * 2);  // 41 MB
    float* hbuf   = (float*)alloc((size_t)NNODES * HIDDIM * 4);
    float* obuf   = (float*)alloc((size_t)NNODES * HIDDIM * 4);
    float* sb     = (float*)alloc((size_t)NNODES * HIDDIM * 4);
    int*   deg    = (int*)alloc((2 * NNODES + 128 + 4 * 256) * 4);
    int*   cursor = deg + NNODES;
    int*   gs     = deg + 2 * NNODES;
    int*   ge     = gs + NGRAPH;
    float* bnstat4 = (float*)(deg + 2 * NNODES + 128);
    int*   chunk  = (int*)alloc(NNODES * 4);
    int*   bsum   = (int*)alloc(128 * 4);
    int*   offs   = (int*)alloc((NNODES + 1) * 4);
    int*   csrsrc = (int*)alloc(NEDGES * 4);

    unsigned short* WtQKV = WtAll;                       // [3][384][KC]
    unsigned short* WtS   = WtAll + (size_t)1152 * KC;   // [3][128][KC]
    unsigned short* Wpt   = WtAll + (size_t)1536 * KC;
    unsigned short* Ws3t  = WtAll + (size_t)1664 * KC;
    unsigned short* Wt3   = WtAll + (size_t)1792 * KC;   // [8][384][KC]
    float* bQKV = bcat;          // [3][384]
    float* bS   = bcat + 1152;   // [3][128]
    float* b3   = bcat + 1536;   // [3072]
    unsigned short* qkvb = qkv3b;  // layers 0-2 alias: [N][384]

    const int TB = 256;
    const int ZWORDS = 2 * NNODES + 128 + 4 * 256;
    zero_kernel<<<(ZWORDS + TB - 1) / TB, TB, 0, stream>>>((float*)deg, ZWORDS);
    count_deg_kernel<<<(NEDGES + TB - 1) / TB, TB, 0, stream>>>(edst, deg, NEDGES);
    const int NB = (NNODES + 255) / 256;
    scan1_kernel<<<NB, 256, 0, stream>>>(deg, chunk, bsum, NNODES);
    scan2_kernel<<<1, 128, 0, stream>>>(bsum, NB);
    scan3_kernel<<<NB, 256, 0, stream>>>(chunk, bsum, offs, NNODES);
    scatter_kernel<<<(NEDGES + TB - 1) / TB, TB, 0, stream>>>(esrc, edst, offs, cursor, csrsrc, NEDGES);
    gb_kernel<<<(NNODES + TB - 1) / TB, TB, 0, stream>>>(batch, gs, ge, NNODES);

    prep_w_kernel<<<4864, 128, 0, stream>>>(Wq, Wk, Wv, Ws, Wp, Ws3, Wq3, Wk3, Wv3, WtAll);
    prep_bias_kernel<<<(4608 + TB - 1) / TB, TB, 0, stream>>>(bq, bk, bv, bs, bq3, bk3, bv3, bcat);

    const int CATB = (NPAD * HIDDIM + TB - 1) / TB;
    const int GSW = 8 * ((GXTILES + 7) / 8);  // 160 swizzled x-slots

    cat_from_kernel<<<CATB, TB, 0, stream>>>(x, Acat);
    gemm_mfma_kernel<float, 12, 1><<<GSW * 1, 256, 0, stream>>>(Acat, Wpt, bp, hbuf, 128, NNODES);
    cat_from_kernel<<<CATB, TB, 0, stream>>>(hbuf, Acat);

    for (int li = 0; li < 3; ++li) {
        gemm_mfma_kernel<unsigned short, 8, 3><<<GSW * 3, 256, 0, stream>>>(
            Acat, WtQKV + (size_t)li * 384 * KC, bQKV + li * 384, qkvb, 384, NNODES);
        gemm_mfma_kernel<float, 12, 1><<<GSW * 1, 256, 0, stream>>>(
            Acat, WtS + (size_t)li * 128 * KC, bS + li * 128, sfp, 128, NNODES);
        attn_small_kernel<<<NNODES, 64, 0, stream>>>(qkvb, sfp, Wbeta + li * 384,
                                                     offs, csrsrc, obuf);
        float* st = bnstat4 + li * 256;
        bn_stats_kernel<<<640, 128, 0, stream>>>(obuf, st, NNODES);
        bn_apply_kernel<<<512, 128, 0, stream>>>(obuf, st, bn_gamma + li * HIDDIM,
                                                 bn_beta + li * HIDDIM, NNODES, Acat);
    }

    // ---- layer 3: single merged q|k|v GEMM (8 heads) + single attention ----
    gemm_mfma_kernel<unsigned short, 8, 24><<<GSW * 24, 256, 0, stream>>>(
        Acat, Wt3, b3, qkv3b, 3072, NNODES);
    attn_big_kernel<<<dim3(NNODES, 8), 64, 0, stream>>>(qkv3b, offs, csrsrc, obuf8);
    gemm_mfma_kernel<float, 12, 1><<<GSW * 1, 256, 0, stream>>>(Acat, Ws3t, bs3, sb, 128, NNODES);
    beta3_kernel<<<NNODES, 128, 0, stream>>>(obuf8, sb, Wbeta3, hbuf);
    float* st3 = bnstat4 + 3 * 256;
    bn_stats_kernel<<<640, 128, 0, stream>>>(hbuf, st3, NNODES);
    bn_apply_kernel<<<512, 128, 0, stream>>>(hbuf, st3, bn_gamma + 3 * HIDDIM,
                                             bn_beta + 3 * HIDDIM, NNODES, (unsigned short*)0);

    zero_kernel<<<(NGRAPH * HIDDIM + TB - 1) / TB, TB, 0, stream>>>(out, NGRAPH * HIDDIM);
    pool_part_kernel<<<dim3(NGRAPH, 8), 256, 0, stream>>>(hbuf, gs, ge, out);
    pool_div_kernel<<<NGRAPH, 128, 0, stream>>>(out, gs, ge);
}